// Round 2
// baseline (221.322 us; speedup 1.0000x reference)
//
#include <hip/hip_runtime.h>
#include <hip/hip_fp16.h>

#define IN_F 128
#define OUT_F 32
#define R_NODES 256          // dst nodes per bucket (8 bits)
#define RSHIFT 8
#define RMASK 255
#define BKT_CAP 7168         // Poisson(4092) + chunk padding (~5720 exp) + 9+ sigma
#define OVF_CAP 4096
#define EPB 8192             // edges per build sub-block (round-8 proven)
#define MAXNB 512            // max buckets => n_nodes <= 131072
#define SENT 0xFFFFFFFFu     // pad sentinel in bkt (skipped by sortgather)

// ---------------------------------------------------------------------------
// ROUND 2: attribution split. mega_kernel's 88.8us is either build-bound (A)
// or linear-bound (B) -- the fused dispatch hides which. Since one side
// dominating means max(Ta,Tb) ~= Ta+Tb, splitting costs ~nothing and gives
// each phase its own rocprof row. Linear additionally moves to 256-thread
// blocks (782 of them, 16KB LDS, 8/CU schedulable) instead of being forced
// into the 1024-thread 54.5KB-union block.
// Reverted: round-1 out_cnt XCD-partitioning (measured null: WRITE_SIZE and
// dur unchanged -> device atomics resolve at fabric regardless of XCD).
// ---------------------------------------------------------------------------
struct BuildSmem {
    unsigned sorted[EPB];        // 32 KB
    unsigned short binof[EPB];   // 16 KB
    int hist[MAXNB];             // count, then cursor
    int lbase[MAXNB];
    int gbase[MAXNB];
    int wsum[16];
};

__global__ __launch_bounds__(1024) void build_kernel(
    const int* __restrict__ src, const int* __restrict__ dst,
    int* __restrict__ out_cnt, int* __restrict__ in_cnt,
    int* __restrict__ gcur, unsigned* __restrict__ bkt,
    int* __restrict__ ovf, int* __restrict__ ovf_cnt,
    int n_edges) {

    __shared__ BuildSmem sm;
    int tid = threadIdx.x;
    int sub = blockIdx.x;

    int e0 = sub * EPB;
    int ecnt = min(EPB, n_edges - e0);

    if (tid < MAXNB) sm.hist[tid] = 0;
    __syncthreads();

    // sweep 1: src-degree atomics + bin histogram
    for (int k = tid; k < ecnt; k += 1024) {
        int e = e0 + k;
        int s = src[e], d = dst[e];
        atomicAdd(&out_cnt[s], 1);
        atomicAdd(&sm.hist[d >> RSHIFT], 1);
    }
    __syncthreads();

    // block scan (tid>=MAXNB contribute 0) + LINE-ALIGNED chunk reserve
    int cnt = (tid < MAXNB) ? sm.hist[tid] : 0;
    int lane = tid & 63, wid = tid >> 6;
    int scan = cnt;
    for (int off = 1; off < 64; off <<= 1) {
        int v = __shfl_up(scan, off, 64);
        if (lane >= off) scan += v;
    }
    if (lane == 63) sm.wsum[wid] = scan;
    __syncthreads();
    int woff = 0;
    for (int w = 0; w < wid; ++w) woff += sm.wsum[w];
    int excl = woff + scan - cnt;
    if (tid < MAXNB) {
        sm.lbase[tid] = excl;
        sm.hist[tid]  = excl;           // becomes insertion cursor
        int res = (cnt + 15) & ~15;     // whole 64B lines
        if (cnt > 0) sm.gbase[tid] = atomicAdd(&gcur[tid], res);
    }
    __syncthreads();

    // sweep 2: local counting-sort into LDS
    for (int k = tid; k < ecnt; k += 1024) {
        int e = e0 + k;
        int s = src[e], d = dst[e];
        int bin = d >> RSHIFT;
        int idx = atomicAdd(&sm.hist[bin], 1);
        sm.sorted[idx] = ((unsigned)s << RSHIFT) | (unsigned)(d & RMASK);
        sm.binof[idx]  = (unsigned short)bin;
    }
    __syncthreads();

    // sweep 3: dense line-aligned flush + sentinel pad fill
    for (int i = tid; i < ecnt; i += 1024) {
        unsigned v = sm.sorted[i];
        int bin = sm.binof[i];
        int gpos = sm.gbase[bin] + (i - sm.lbase[bin]);
        if (gpos < BKT_CAP) {
            bkt[(size_t)bin * BKT_CAP + gpos] = v;
        } else {
            int d = bin * R_NODES + (int)(v & RMASK);
            atomicAdd(&in_cnt[d], 1);   // overflow-only in-degree
            int o = atomicAdd(ovf_cnt, 1);
            if (o < OVF_CAP) {
                ovf[2 * o]     = (int)(v >> RSHIFT);
                ovf[2 * o + 1] = d;
            }
        }
    }
    for (int bin = tid; bin < MAXNB; bin += 1024) {
        int bc  = sm.hist[bin] - sm.lbase[bin];   // real count
        int res = (bc + 15) & ~15;
        for (int p = bc; p < res; ++p) {
            int gpos = sm.gbase[bin] + p;
            if (gpos < BKT_CAP) bkt[(size_t)bin * BKT_CAP + gpos] = SENT;
        }
    }
}

// ---------------------------------------------------------------------------
// Linear: tmp(fp16) = feat @ W, UNSCALED (src scale folded in by scale_tmp).
// 256-thread blocks, 128 rows each: 782 blocks, 16KB LDS, 8 blocks/CU.
// ---------------------------------------------------------------------------
__global__ __launch_bounds__(256) void linear_kernel(
    const float* __restrict__ feat, const float* __restrict__ weight,
    __half* __restrict__ tmp, int n_nodes) {
    __shared__ float w[IN_F * OUT_F];
    {
        const float4* wg = (const float4*)weight;
        float4* wsh = (float4*)w;
        for (int i = threadIdx.x; i < IN_F * OUT_F / 4; i += 256) wsh[i] = wg[i];
    }
    __syncthreads();
    int q  = threadIdx.x >> 3;          // 0..31 row-quads
    int cg = threadIdx.x & 7;           // col group of 4
    int row0 = blockIdx.x * 128 + q * 4;
    if (row0 >= n_nodes) return;
    int rmax = n_nodes - row0;
    if (rmax > 4) rmax = 4;
    const float4* feat4 = (const float4*)feat;
    float4 acc[4];
#pragma unroll
    for (int r = 0; r < 4; ++r) acc[r] = make_float4(0.f, 0.f, 0.f, 0.f);
    for (int k4 = 0; k4 < IN_F / 4; ++k4) {
        float4 wv0 = *(const float4*)&w[(4 * k4 + 0) * OUT_F + 4 * cg];
        float4 wv1 = *(const float4*)&w[(4 * k4 + 1) * OUT_F + 4 * cg];
        float4 wv2 = *(const float4*)&w[(4 * k4 + 2) * OUT_F + 4 * cg];
        float4 wv3 = *(const float4*)&w[(4 * k4 + 3) * OUT_F + 4 * cg];
#pragma unroll
        for (int r = 0; r < 4; ++r) {
            int rr = (r < rmax) ? r : 0;
            float4 f = feat4[(size_t)(row0 + rr) * (IN_F / 4) + k4];
            acc[r].x += f.x * wv0.x + f.y * wv1.x + f.z * wv2.x + f.w * wv3.x;
            acc[r].y += f.x * wv0.y + f.y * wv1.y + f.z * wv2.y + f.w * wv3.y;
            acc[r].z += f.x * wv0.z + f.y * wv1.z + f.z * wv2.z + f.w * wv3.z;
            acc[r].w += f.x * wv0.w + f.y * wv1.w + f.z * wv2.w + f.w * wv3.w;
        }
    }
#pragma unroll
    for (int r = 0; r < 4; ++r) {
        if (r < rmax) {
            union { __half h[4]; uint2 u; } pk;
            pk.h[0] = __float2half(acc[r].x);
            pk.h[1] = __float2half(acc[r].y);
            pk.h[2] = __float2half(acc[r].z);
            pk.h[3] = __float2half(acc[r].w);
            *(uint2*)&tmp[(size_t)(row0 + r) * OUT_F + 4 * cg] = pk.u;
        }
    }
}

// ---------------------------------------------------------------------------
// Fold src-degree scale into tmp in-place (runs after build+linear).
// ---------------------------------------------------------------------------
__global__ __launch_bounds__(256) void scale_tmp(__half* __restrict__ tmp,
                                                 const int* __restrict__ out_cnt,
                                                 int n_nodes) {
    int t = blockIdx.x * 256 + threadIdx.x;
    int node = t >> 2;
    if (node >= n_nodes) return;
    float sc = rsqrtf(fmaxf((float)out_cnt[node], 1.0f));
    uint4* p = (uint4*)(tmp + (size_t)node * OUT_F) + (t & 3);
    uint4 v = *p;
    __half2* h = (__half2*)&v;
#pragma unroll
    for (int i = 0; i < 4; ++i) {
        float2 f = __half22float2(h[i]);
        f.x *= sc; f.y *= sc;
        h[i] = __float22half2_rn(f);
    }
    *p = v;
}

// ---------------------------------------------------------------------------
// Fused sort+gather+overflow: one 1024-thread block per 256-node bucket.
// Gather: 8 lanes x 8B (uint2 = 4 halves/lane), 8-edge batches in flight,
// float4 coalesced store (round-1 win, kept).
// ---------------------------------------------------------------------------
__global__ __launch_bounds__(1024) void sortgather_kernel(
    const unsigned* __restrict__ bkt, const int* __restrict__ gcur,
    const int* __restrict__ in_cnt,
    const int* __restrict__ ovf, const int* __restrict__ ovf_cnt,
    const __half* __restrict__ tmp, float* __restrict__ out, int n_nodes) {

    __shared__ unsigned ent[BKT_CAP];   // 28 KB
    __shared__ unsigned srt[BKT_CAP];   // 28 KB (src ids, node-sorted)
    __shared__ int hist[R_NODES];
    __shared__ int base[R_NODES];
    __shared__ int start[R_NODES];

    int b = blockIdx.x, tid = threadIdx.x;
    int ecnt = min(gcur[b], BKT_CAP);
    const unsigned* gb = bkt + (size_t)b * BKT_CAP;

    if (tid < R_NODES) hist[tid] = 0;
    __syncthreads();

    for (int i = tid; i < ecnt; i += 1024) {
        unsigned v = gb[i];
        ent[i] = v;
        if (v != SENT) atomicAdd(&hist[v & RMASK], 1);
    }
    __syncthreads();

    if (tid < 64) {                      // scan 256 bins, 4/lane
        int a0 = hist[4 * tid], a1 = hist[4 * tid + 1];
        int a2 = hist[4 * tid + 2], a3 = hist[4 * tid + 3];
        int s = a0 + a1 + a2 + a3;
        int sc = s;
        for (int off = 1; off < 64; off <<= 1) {
            int v = __shfl_up(sc, off, 64);
            if (tid >= off) sc += v;
        }
        int excl = sc - s;
        base[4 * tid]     = excl;
        base[4 * tid + 1] = excl + a0;
        base[4 * tid + 2] = excl + a0 + a1;
        base[4 * tid + 3] = excl + a0 + a1 + a2;
    }
    __syncthreads();
    if (tid < R_NODES) start[tid] = base[tid];
    __syncthreads();

    for (int i = tid; i < ecnt; i += 1024) {
        unsigned v = ent[i];
        if (v != SENT) {
            int p = atomicAdd(&base[v & RMASK], 1);
            srt[p] = v >> RSHIFT;        // src only
        }
    }
    __syncthreads();

    int g = tid >> 3;                    // group 0..127 (one node each pass)
    int c = tid & 7;                     // uint2 (4-half) column group
    int n0 = b * R_NODES;
    int novf = min(*ovf_cnt, OVF_CAP);

    for (int ln = g; ln < R_NODES; ln += 128) {
        int node = n0 + ln;
        if (node >= n_nodes) continue;
        int cnt = hist[ln];
        int st  = start[ln];

        float a0 = 0.f, a1 = 0.f, a2 = 0.f, a3 = 0.f;
        float b0 = 0.f, b1 = 0.f, b2 = 0.f, b3 = 0.f;
        int j = 0;
        for (; j + 8 <= cnt; j += 8) {
            int s0 = (int)srt[st + j + 0], s1 = (int)srt[st + j + 1];
            int s2 = (int)srt[st + j + 2], s3 = (int)srt[st + j + 3];
            int s4 = (int)srt[st + j + 4], s5 = (int)srt[st + j + 5];
            int s6 = (int)srt[st + j + 6], s7 = (int)srt[st + j + 7];
            uint2 v0 = *(const uint2*)(tmp + (size_t)s0 * OUT_F + 4 * c);
            uint2 v1 = *(const uint2*)(tmp + (size_t)s1 * OUT_F + 4 * c);
            uint2 v2 = *(const uint2*)(tmp + (size_t)s2 * OUT_F + 4 * c);
            uint2 v3 = *(const uint2*)(tmp + (size_t)s3 * OUT_F + 4 * c);
            uint2 v4 = *(const uint2*)(tmp + (size_t)s4 * OUT_F + 4 * c);
            uint2 v5 = *(const uint2*)(tmp + (size_t)s5 * OUT_F + 4 * c);
            uint2 v6 = *(const uint2*)(tmp + (size_t)s6 * OUT_F + 4 * c);
            uint2 v7 = *(const uint2*)(tmp + (size_t)s7 * OUT_F + 4 * c);
            const __half2* h;
            float2 f;
            h = (const __half2*)&v0;
            f = __half22float2(h[0]); a0 += f.x; a1 += f.y;
            f = __half22float2(h[1]); a2 += f.x; a3 += f.y;
            h = (const __half2*)&v1;
            f = __half22float2(h[0]); b0 += f.x; b1 += f.y;
            f = __half22float2(h[1]); b2 += f.x; b3 += f.y;
            h = (const __half2*)&v2;
            f = __half22float2(h[0]); a0 += f.x; a1 += f.y;
            f = __half22float2(h[1]); a2 += f.x; a3 += f.y;
            h = (const __half2*)&v3;
            f = __half22float2(h[0]); b0 += f.x; b1 += f.y;
            f = __half22float2(h[1]); b2 += f.x; b3 += f.y;
            h = (const __half2*)&v4;
            f = __half22float2(h[0]); a0 += f.x; a1 += f.y;
            f = __half22float2(h[1]); a2 += f.x; a3 += f.y;
            h = (const __half2*)&v5;
            f = __half22float2(h[0]); b0 += f.x; b1 += f.y;
            f = __half22float2(h[1]); b2 += f.x; b3 += f.y;
            h = (const __half2*)&v6;
            f = __half22float2(h[0]); a0 += f.x; a1 += f.y;
            f = __half22float2(h[1]); a2 += f.x; a3 += f.y;
            h = (const __half2*)&v7;
            f = __half22float2(h[0]); b0 += f.x; b1 += f.y;
            f = __half22float2(h[1]); b2 += f.x; b3 += f.y;
        }
        for (; j < cnt; ++j) {
            int s = (int)srt[st + j];
            uint2 v = *(const uint2*)(tmp + (size_t)s * OUT_F + 4 * c);
            const __half2* h = (const __half2*)&v;
            float2 f;
            if (j & 1) {
                f = __half22float2(h[0]); b0 += f.x; b1 += f.y;
                f = __half22float2(h[1]); b2 += f.x; b3 += f.y;
            } else {
                f = __half22float2(h[0]); a0 += f.x; a1 += f.y;
                f = __half22float2(h[1]); a2 += f.x; a3 += f.y;
            }
        }
        for (int e2 = 0; e2 < novf; ++e2) {        // ~always empty
            if (ovf[2 * e2 + 1] == node) {
                uint2 v = *(const uint2*)(tmp + (size_t)ovf[2 * e2] * OUT_F + 4 * c);
                const __half2* h = (const __half2*)&v;
                float2 f;
                f = __half22float2(h[0]); a0 += f.x; a1 += f.y;
                f = __half22float2(h[1]); a2 += f.x; a3 += f.y;
            }
        }

        float dg = (float)(cnt + in_cnt[node]);
        float sc = rsqrtf(fmaxf(dg, 1.0f));
        float4 o = make_float4((a0 + b0) * sc, (a1 + b1) * sc,
                               (a2 + b2) * sc, (a3 + b3) * sc);
        *(float4*)(out + (size_t)node * OUT_F + 4 * c) = o;
    }
}

// ---------------------------------------------------------------------------
// Fallback path (ws too small): degree + scaled-linear + atomic scatter.
// ---------------------------------------------------------------------------
__global__ void degree_kernel(const int* __restrict__ src, const int* __restrict__ dst,
                              int* __restrict__ out_cnt, int* __restrict__ in_cnt,
                              int n_edges) {
    int i = blockIdx.x * blockDim.x + threadIdx.x;
    if (i < n_edges) {
        atomicAdd(&out_cnt[src[i]], 1);
        atomicAdd(&in_cnt[dst[i]], 1);
    }
}

__global__ __launch_bounds__(256) void linear_fb(const float* __restrict__ feat,
                                                 const float* __restrict__ weight,
                                                 const int* __restrict__ out_cnt,
                                                 __half* __restrict__ tmp, int n_nodes) {
    __shared__ float w[IN_F * OUT_F];
    {
        const float4* wg = (const float4*)weight;
        float4* wsh = (float4*)w;
        for (int i = threadIdx.x; i < IN_F * OUT_F / 4; i += 256) wsh[i] = wg[i];
    }
    __syncthreads();
    int q  = threadIdx.x >> 3;
    int cg = threadIdx.x & 7;
    int row0 = blockIdx.x * 128 + q * 4;
    if (row0 >= n_nodes) return;
    int rmax = n_nodes - row0;
    if (rmax > 4) rmax = 4;
    const float4* feat4 = (const float4*)feat;
    float4 acc[4];
#pragma unroll
    for (int r = 0; r < 4; ++r) acc[r] = make_float4(0.f, 0.f, 0.f, 0.f);
    for (int k4 = 0; k4 < IN_F / 4; ++k4) {
        float4 wv0 = *(const float4*)&w[(4 * k4 + 0) * OUT_F + 4 * cg];
        float4 wv1 = *(const float4*)&w[(4 * k4 + 1) * OUT_F + 4 * cg];
        float4 wv2 = *(const float4*)&w[(4 * k4 + 2) * OUT_F + 4 * cg];
        float4 wv3 = *(const float4*)&w[(4 * k4 + 3) * OUT_F + 4 * cg];
#pragma unroll
        for (int r = 0; r < 4; ++r) {
            int rr = (r < rmax) ? r : 0;
            float4 f = feat4[(size_t)(row0 + rr) * (IN_F / 4) + k4];
            acc[r].x += f.x * wv0.x + f.y * wv1.x + f.z * wv2.x + f.w * wv3.x;
            acc[r].y += f.x * wv0.y + f.y * wv1.y + f.z * wv2.y + f.w * wv3.y;
            acc[r].z += f.x * wv0.z + f.y * wv1.z + f.z * wv2.z + f.w * wv3.z;
            acc[r].w += f.x * wv0.w + f.y * wv1.w + f.z * wv2.w + f.w * wv3.w;
        }
    }
#pragma unroll
    for (int r = 0; r < 4; ++r) {
        if (r < rmax) {
            float sc = rsqrtf(fmaxf((float)out_cnt[row0 + r], 1.0f));
            union { __half h[4]; uint2 u; } pk;
            pk.h[0] = __float2half(acc[r].x * sc);
            pk.h[1] = __float2half(acc[r].y * sc);
            pk.h[2] = __float2half(acc[r].z * sc);
            pk.h[3] = __float2half(acc[r].w * sc);
            *(uint2*)&tmp[(size_t)(row0 + r) * OUT_F + 4 * cg] = pk.u;
        }
    }
}

__global__ void scatter_kernel(const int* __restrict__ src, const int* __restrict__ dst,
                               const __half* __restrict__ tmp, float* __restrict__ out,
                               int n_edges) {
    long long t = (long long)blockIdx.x * blockDim.x + threadIdx.x;
    int e = (int)(t >> 5);
    int c = (int)(t & (OUT_F - 1));
    if (e < n_edges) {
        atomicAdd(&out[(size_t)dst[e] * OUT_F + c],
                  __half2float(tmp[(size_t)src[e] * OUT_F + c]));
    }
}

__global__ void finalize_kernel(float* __restrict__ out, const int* __restrict__ in_cnt,
                                int n_total) {
    int t = blockIdx.x * blockDim.x + threadIdx.x;
    if (t < n_total) {
        out[t] *= rsqrtf(fmaxf((float)in_cnt[t >> 5], 1.0f));
    }
}

extern "C" void kernel_launch(void* const* d_in, const int* in_sizes, int n_in,
                              void* d_out, int out_size, void* d_ws, size_t ws_size,
                              hipStream_t stream) {
    const float* feat   = (const float*)d_in[0];
    const int*   src    = (const int*)d_in[1];
    const int*   dst    = (const int*)d_in[2];
    const float* weight = (const float*)d_in[3];
    float*       out    = (float*)d_out;

    int n_nodes = in_sizes[0] / IN_F;   // 100000
    int n_edges = in_sizes[1];          // 1600000
    int n_buckets = (n_nodes + R_NODES - 1) / R_NODES;  // 391 (<= MAXNB)

    // ws layout: [out_cnt n][in_cnt n][gcur MAXNB][ovf_cnt 8][ovf 2*CAP]
    //            [bkt nb*BKT_CAP][tmp fp16 n*32]
    int*      out_cnt = (int*)d_ws;
    int*      in_cnt  = out_cnt + n_nodes;
    int*      gcur    = in_cnt + n_nodes;
    int*      ovf_cnt = gcur + MAXNB;
    int*      ovf     = ovf_cnt + 8;
    unsigned* bkt     = (unsigned*)(ovf + 2 * OVF_CAP);
    __half*   tmp     = (__half*)(bkt + (size_t)n_buckets * BKT_CAP);
    size_t    needed  = (char*)(tmp + (size_t)n_nodes * OUT_F) - (char*)d_ws;

    if (ws_size >= needed && n_buckets <= MAXNB) {
        hipMemsetAsync(out_cnt, 0, ((size_t)2 * n_nodes + MAXNB + 8) * sizeof(int), stream);
        int n_bbl = (n_edges + EPB - 1) / EPB;          // 196
        build_kernel<<<n_bbl, 1024, 0, stream>>>(
            src, dst, out_cnt, in_cnt, gcur, bkt, ovf, ovf_cnt, n_edges);
        linear_kernel<<<(n_nodes + 127) / 128, 256, 0, stream>>>(
            feat, weight, tmp, n_nodes);
        scale_tmp<<<(n_nodes * 4 + 255) / 256, 256, 0, stream>>>(tmp, out_cnt, n_nodes);
        sortgather_kernel<<<n_buckets, 1024, 0, stream>>>(
            bkt, gcur, in_cnt, ovf, ovf_cnt, tmp, out, n_nodes);
    } else {
        // fallback: atomic scatter
        __half* tmp_fb = (__half*)(ovf + 2 * OVF_CAP);
        hipMemsetAsync(out_cnt, 0, ((size_t)2 * n_nodes + MAXNB + 8) * sizeof(int), stream);
        hipMemsetAsync(d_out, 0, (size_t)out_size * sizeof(float), stream);
        degree_kernel<<<(n_edges + 255) / 256, 256, 0, stream>>>(src, dst, out_cnt, in_cnt, n_edges);
        linear_fb<<<(n_nodes + 127) / 128, 256, 0, stream>>>(feat, weight, out_cnt, tmp_fb, n_nodes);
        long long st = (long long)n_edges * OUT_F;
        scatter_kernel<<<(int)((st + 255) / 256), 256, 0, stream>>>(src, dst, tmp_fb, out, n_edges);
        finalize_kernel<<<(n_nodes * OUT_F + 255) / 256, 256, 0, stream>>>(out, in_cnt, n_nodes * OUT_F);
    }
}

// Round 3
// 194.374 us; speedup vs baseline: 1.1386x; 1.1386x over previous
//
#include <hip/hip_runtime.h>
#include <hip/hip_fp16.h>

#define IN_F 128
#define OUT_F 32
#define R_NODES 256          // dst nodes per bucket (8 bits)
#define RSHIFT 8
#define RMASK 255
#define BKT_CAP 7168         // dst buckets: Poisson(4092) + 16-pad (~5720 exp) + 9 sigma
#define BKT2_CAP 8192        // src buckets: 4092 + 32-pad*196 (~7230 exp) + ~6.7 sigma
#define OVF_CAP 4096
#define EPB 8192             // edges per build sub-block
#define MAXNB 512            // max buckets => n_nodes <= 131072
#define SENT 0xFFFFFFFFu     // pad sentinel in bkt (u32)
#define SENT2 0xFFFFu        // pad sentinel in bkt2 (u16)

// ---------------------------------------------------------------------------
// ROUND 3. Round-2 attribution: build=75us, VALUBusy 2.5%, WRITE 59MB with
// only ~9MB real stores -> the 1.6M device-scope out_cnt atomics are the
// bottleneck (fabric atomic throughput ~21G/s; round-1 showed XCD
// partitioning can't help). Fix: REMOVE all fabric atomics. Build gains a
// second LDS counting sort (phase S) that buckets src low-bytes into bkt2
// (ushort, SENT2 pads, 64B-aligned chunks); scale_tmp histograms each
// bucket in LDS to recover out-degree. Also re-fuse build'||linear (round-2
// split cost ~20us).
// ---------------------------------------------------------------------------
struct BuildSmem {                   // phase D (dst sort)
    unsigned sorted[EPB];            // 32 KB
    unsigned short binof[EPB];       // 16 KB
    int hist[MAXNB];
    int lbase[MAXNB];
    int gbase[MAXNB];
    int wsum[16];
};
struct BuildSmemS {                  // phase S (src sort), reuses same LDS
    unsigned short sorted[EPB];      // 16 KB (src & 255)
    unsigned short binof[EPB];       // 16 KB (src >> 8)
    int hist[MAXNB];
    int lbase[MAXNB];
    int gbase[MAXNB];
    int wsum[16];
};
struct LinSmem { float w[IN_F * OUT_F]; };
union MegaSmem { BuildSmem b; BuildSmemS s; LinSmem l; };

__global__ __launch_bounds__(1024) void mega_kernel(
    const int* __restrict__ src, const int* __restrict__ dst,
    const float* __restrict__ feat, const float* __restrict__ weight,
    int* __restrict__ out_cnt, int* __restrict__ in_cnt,
    int* __restrict__ gcur, int* __restrict__ gcur2,
    unsigned* __restrict__ bkt, unsigned short* __restrict__ bkt2,
    int* __restrict__ ovf, int* __restrict__ ovf_cnt,
    __half* __restrict__ tmp, int n_edges, int n_nodes,
    int n_bbl, int n_lbl) {

    __shared__ MegaSmem sm;
    int tid = threadIdx.x;
    int bid = blockIdx.x;

    // parity interleave: even -> build, odd -> linear (tail: whoever is left)
    int m2 = 2 * min(n_bbl, n_lbl);
    bool is_build;
    int sub;
    if (bid < m2) { is_build = ((bid & 1) == 0); sub = bid >> 1; }
    else          { is_build = (n_bbl > n_lbl);  sub = m2 / 2 + (bid - m2); }

    if (is_build) {
        int e0 = sub * EPB;
        int ecnt = min(EPB, n_edges - e0);
        int lane = tid & 63, wid = tid >> 6;

        // ================= phase D: dst-bucket (s<<8|dlow) =================
        if (tid < MAXNB) sm.b.hist[tid] = 0;
        __syncthreads();

        // sweep 1: bin histogram ONLY (no fabric atomics any more)
        for (int k = tid; k < ecnt; k += 1024) {
            atomicAdd(&sm.b.hist[dst[e0 + k] >> RSHIFT], 1);
        }
        __syncthreads();

        // block scan + LINE-ALIGNED chunk reserve
        int cnt = (tid < MAXNB) ? sm.b.hist[tid] : 0;
        int scan = cnt;
        for (int off = 1; off < 64; off <<= 1) {
            int v = __shfl_up(scan, off, 64);
            if (lane >= off) scan += v;
        }
        if (lane == 63) sm.b.wsum[wid] = scan;
        __syncthreads();
        int woff = 0;
        for (int w = 0; w < wid; ++w) woff += sm.b.wsum[w];
        int excl = woff + scan - cnt;
        if (tid < MAXNB) {
            sm.b.lbase[tid] = excl;
            sm.b.hist[tid]  = excl;         // becomes insertion cursor
            int res = (cnt + 15) & ~15;     // whole 64B lines (u32)
            if (cnt > 0) sm.b.gbase[tid] = atomicAdd(&gcur[tid], res);
        }
        __syncthreads();

        // sweep 2: local counting-sort into LDS
        for (int k = tid; k < ecnt; k += 1024) {
            int e = e0 + k;
            int s = src[e], d = dst[e];
            int bin = d >> RSHIFT;
            int idx = atomicAdd(&sm.b.hist[bin], 1);
            sm.b.sorted[idx] = ((unsigned)s << RSHIFT) | (unsigned)(d & RMASK);
            sm.b.binof[idx]  = (unsigned short)bin;
        }
        __syncthreads();

        // sweep 3: dense line-aligned flush + sentinel pad fill
        for (int i = tid; i < ecnt; i += 1024) {
            unsigned v = sm.b.sorted[i];
            int bin = sm.b.binof[i];
            int gpos = sm.b.gbase[bin] + (i - sm.b.lbase[bin]);
            if (gpos < BKT_CAP) {
                bkt[(size_t)bin * BKT_CAP + gpos] = v;
            } else {
                int d = bin * R_NODES + (int)(v & RMASK);
                atomicAdd(&in_cnt[d], 1);   // overflow-only in-degree
                int o = atomicAdd(ovf_cnt, 1);
                if (o < OVF_CAP) {
                    ovf[2 * o]     = (int)(v >> RSHIFT);
                    ovf[2 * o + 1] = d;
                }
            }
        }
        for (int bin = tid; bin < MAXNB; bin += 1024) {
            int bc  = sm.b.hist[bin] - sm.b.lbase[bin];   // real count
            int res = (bc + 15) & ~15;
            for (int p = bc; p < res; ++p) {
                int gpos = sm.b.gbase[bin] + p;
                if (gpos < BKT_CAP) bkt[(size_t)bin * BKT_CAP + gpos] = SENT;
            }
        }
        __syncthreads();   // phase D LDS dead from here

        // ============ phase S: src-bucket low bytes (out-degree) ============
        if (tid < MAXNB) sm.s.hist[tid] = 0;
        __syncthreads();

        for (int k = tid; k < ecnt; k += 1024) {
            atomicAdd(&sm.s.hist[src[e0 + k] >> RSHIFT], 1);
        }
        __syncthreads();

        cnt = (tid < MAXNB) ? sm.s.hist[tid] : 0;
        scan = cnt;
        for (int off = 1; off < 64; off <<= 1) {
            int v = __shfl_up(scan, off, 64);
            if (lane >= off) scan += v;
        }
        if (lane == 63) sm.s.wsum[wid] = scan;
        __syncthreads();
        woff = 0;
        for (int w = 0; w < wid; ++w) woff += sm.s.wsum[w];
        excl = woff + scan - cnt;
        if (tid < MAXNB) {
            sm.s.lbase[tid] = excl;
            sm.s.hist[tid]  = excl;
            int res = (cnt + 31) & ~31;     // whole 64B lines (u16)
            if (cnt > 0) sm.s.gbase[tid] = atomicAdd(&gcur2[tid], res);
        }
        __syncthreads();

        for (int k = tid; k < ecnt; k += 1024) {
            int s = src[e0 + k];
            int bin = s >> RSHIFT;
            int idx = atomicAdd(&sm.s.hist[bin], 1);
            sm.s.sorted[idx] = (unsigned short)(s & RMASK);
            sm.s.binof[idx]  = (unsigned short)bin;
        }
        __syncthreads();

        for (int i = tid; i < ecnt; i += 1024) {
            unsigned short v = sm.s.sorted[i];
            int bin = sm.s.binof[i];
            int gpos = sm.s.gbase[bin] + (i - sm.s.lbase[bin]);
            if (gpos < BKT2_CAP) {
                bkt2[(size_t)bin * BKT2_CAP + gpos] = v;
            } else {
                atomicAdd(&out_cnt[bin * R_NODES + (int)v], 1);  // rare
            }
        }
        for (int bin = tid; bin < MAXNB; bin += 1024) {
            int bc  = sm.s.hist[bin] - sm.s.lbase[bin];
            int res = (bc + 31) & ~31;
            for (int p = bc; p < res; ++p) {
                int gpos = sm.s.gbase[bin] + p;
                if (gpos < BKT2_CAP) bkt2[(size_t)bin * BKT2_CAP + gpos] = SENT2;
            }
        }
    } else {
        // ===== linear: tmp(fp16) = feat @ W, UNSCALED =====
        if (tid < 1024) ((float4*)sm.l.w)[tid] = ((const float4*)weight)[tid];
        __syncthreads();

        int q  = tid >> 3;                  // 0..127 row-quads
        int cg = tid & 7;                   // col group of 4
        int row0 = sub * 512 + q * 4;
        if (row0 >= n_nodes) return;
        int rmax = n_nodes - row0;
        if (rmax > 4) rmax = 4;

        const float4* feat4 = (const float4*)feat;
        float4 acc[4];
#pragma unroll
        for (int r = 0; r < 4; ++r) acc[r] = make_float4(0.f, 0.f, 0.f, 0.f);

        for (int k4 = 0; k4 < IN_F / 4; ++k4) {
            float4 wv0 = *(const float4*)&sm.l.w[(4 * k4 + 0) * OUT_F + 4 * cg];
            float4 wv1 = *(const float4*)&sm.l.w[(4 * k4 + 1) * OUT_F + 4 * cg];
            float4 wv2 = *(const float4*)&sm.l.w[(4 * k4 + 2) * OUT_F + 4 * cg];
            float4 wv3 = *(const float4*)&sm.l.w[(4 * k4 + 3) * OUT_F + 4 * cg];
#pragma unroll
            for (int r = 0; r < 4; ++r) {
                int rr = (r < rmax) ? r : 0;
                float4 f = feat4[(size_t)(row0 + rr) * (IN_F / 4) + k4];
                acc[r].x += f.x * wv0.x + f.y * wv1.x + f.z * wv2.x + f.w * wv3.x;
                acc[r].y += f.x * wv0.y + f.y * wv1.y + f.z * wv2.y + f.w * wv3.y;
                acc[r].z += f.x * wv0.z + f.y * wv1.z + f.z * wv2.z + f.w * wv3.z;
                acc[r].w += f.x * wv0.w + f.y * wv1.w + f.z * wv2.w + f.w * wv3.w;
            }
        }

#pragma unroll
        for (int r = 0; r < 4; ++r) {
            if (r < rmax) {
                union { __half h[4]; uint2 u; } pk;
                pk.h[0] = __float2half(acc[r].x);
                pk.h[1] = __float2half(acc[r].y);
                pk.h[2] = __float2half(acc[r].z);
                pk.h[3] = __float2half(acc[r].w);
                *(uint2*)&tmp[(size_t)(row0 + r) * OUT_F + 4 * cg] = pk.u;
            }
        }
    }
}

// ---------------------------------------------------------------------------
// scale_tmp: one block per src-bucket. LDS-histogram bkt2 low-bytes ->
// out-degree (plus rare out_cnt overflow adds) -> fold rsqrt scale into tmp.
// Replaces 1.6M fabric atomics with 1.6M per-CU LDS atomics.
// ---------------------------------------------------------------------------
__global__ __launch_bounds__(256) void scale_tmp(
    const unsigned short* __restrict__ bkt2, const int* __restrict__ gcur2,
    const int* __restrict__ out_cnt, __half* __restrict__ tmp, int n_nodes) {
    __shared__ int hist[R_NODES];
    __shared__ float scf[R_NODES];
    int b = blockIdx.x, tid = threadIdx.x;

    hist[tid] = 0;
    __syncthreads();

    int ecnt = min(gcur2[b], BKT2_CAP);
    const unsigned short* gb = bkt2 + (size_t)b * BKT2_CAP;
    for (int i = tid; i < ecnt; i += 256) {
        unsigned v = gb[i];
        if (v != SENT2) atomicAdd(&hist[v], 1);
    }
    __syncthreads();

    int node = b * R_NODES + tid;
    if (node < n_nodes) {
        int deg = hist[tid] + out_cnt[node];   // overflow adds, usually 0
        scf[tid] = rsqrtf(fmaxf((float)deg, 1.0f));
    }
    __syncthreads();

#pragma unroll
    for (int p = 0; p < 4; ++p) {
        int r = p * 64 + (tid >> 2);
        int nd = b * R_NODES + r;
        if (nd >= n_nodes) continue;
        float sc = scf[r];
        uint4* ptr = (uint4*)(tmp + (size_t)nd * OUT_F) + (tid & 3);
        uint4 v = *ptr;
        __half2* h = (__half2*)&v;
#pragma unroll
        for (int i = 0; i < 4; ++i) {
            float2 f = __half22float2(h[i]);
            f.x *= sc; f.y *= sc;
            h[i] = __float22half2_rn(f);
        }
        *ptr = v;
    }
}

// ---------------------------------------------------------------------------
// Fused sort+gather+overflow: one 1024-thread block per 256-node bucket.
// Gather: 8 lanes x 8B (uint2), 8-edge batches, float4 store (round-1 win).
// ---------------------------------------------------------------------------
__global__ __launch_bounds__(1024) void sortgather_kernel(
    const unsigned* __restrict__ bkt, const int* __restrict__ gcur,
    const int* __restrict__ in_cnt,
    const int* __restrict__ ovf, const int* __restrict__ ovf_cnt,
    const __half* __restrict__ tmp, float* __restrict__ out, int n_nodes) {

    __shared__ unsigned ent[BKT_CAP];   // 28 KB
    __shared__ unsigned srt[BKT_CAP];   // 28 KB (src ids, node-sorted)
    __shared__ int hist[R_NODES];
    __shared__ int base[R_NODES];
    __shared__ int start[R_NODES];

    int b = blockIdx.x, tid = threadIdx.x;
    int ecnt = min(gcur[b], BKT_CAP);
    const unsigned* gb = bkt + (size_t)b * BKT_CAP;

    if (tid < R_NODES) hist[tid] = 0;
    __syncthreads();

    for (int i = tid; i < ecnt; i += 1024) {
        unsigned v = gb[i];
        ent[i] = v;
        if (v != SENT) atomicAdd(&hist[v & RMASK], 1);
    }
    __syncthreads();

    if (tid < 64) {                      // scan 256 bins, 4/lane
        int a0 = hist[4 * tid], a1 = hist[4 * tid + 1];
        int a2 = hist[4 * tid + 2], a3 = hist[4 * tid + 3];
        int s = a0 + a1 + a2 + a3;
        int sc = s;
        for (int off = 1; off < 64; off <<= 1) {
            int v = __shfl_up(sc, off, 64);
            if (tid >= off) sc += v;
        }
        int excl = sc - s;
        base[4 * tid]     = excl;
        base[4 * tid + 1] = excl + a0;
        base[4 * tid + 2] = excl + a0 + a1;
        base[4 * tid + 3] = excl + a0 + a1 + a2;
    }
    __syncthreads();
    if (tid < R_NODES) start[tid] = base[tid];
    __syncthreads();

    for (int i = tid; i < ecnt; i += 1024) {
        unsigned v = ent[i];
        if (v != SENT) {
            int p = atomicAdd(&base[v & RMASK], 1);
            srt[p] = v >> RSHIFT;        // src only
        }
    }
    __syncthreads();

    int g = tid >> 3;                    // group 0..127 (one node each pass)
    int c = tid & 7;                     // uint2 (4-half) column group
    int n0 = b * R_NODES;
    int novf = min(*ovf_cnt, OVF_CAP);

    for (int ln = g; ln < R_NODES; ln += 128) {
        int node = n0 + ln;
        if (node >= n_nodes) continue;
        int cnt = hist[ln];
        int st  = start[ln];

        float a0 = 0.f, a1 = 0.f, a2 = 0.f, a3 = 0.f;
        float b0 = 0.f, b1 = 0.f, b2 = 0.f, b3 = 0.f;
        int j = 0;
        for (; j + 8 <= cnt; j += 8) {
            int s0 = (int)srt[st + j + 0], s1 = (int)srt[st + j + 1];
            int s2 = (int)srt[st + j + 2], s3 = (int)srt[st + j + 3];
            int s4 = (int)srt[st + j + 4], s5 = (int)srt[st + j + 5];
            int s6 = (int)srt[st + j + 6], s7 = (int)srt[st + j + 7];
            uint2 v0 = *(const uint2*)(tmp + (size_t)s0 * OUT_F + 4 * c);
            uint2 v1 = *(const uint2*)(tmp + (size_t)s1 * OUT_F + 4 * c);
            uint2 v2 = *(const uint2*)(tmp + (size_t)s2 * OUT_F + 4 * c);
            uint2 v3 = *(const uint2*)(tmp + (size_t)s3 * OUT_F + 4 * c);
            uint2 v4 = *(const uint2*)(tmp + (size_t)s4 * OUT_F + 4 * c);
            uint2 v5 = *(const uint2*)(tmp + (size_t)s5 * OUT_F + 4 * c);
            uint2 v6 = *(const uint2*)(tmp + (size_t)s6 * OUT_F + 4 * c);
            uint2 v7 = *(const uint2*)(tmp + (size_t)s7 * OUT_F + 4 * c);
            const __half2* h;
            float2 f;
            h = (const __half2*)&v0;
            f = __half22float2(h[0]); a0 += f.x; a1 += f.y;
            f = __half22float2(h[1]); a2 += f.x; a3 += f.y;
            h = (const __half2*)&v1;
            f = __half22float2(h[0]); b0 += f.x; b1 += f.y;
            f = __half22float2(h[1]); b2 += f.x; b3 += f.y;
            h = (const __half2*)&v2;
            f = __half22float2(h[0]); a0 += f.x; a1 += f.y;
            f = __half22float2(h[1]); a2 += f.x; a3 += f.y;
            h = (const __half2*)&v3;
            f = __half22float2(h[0]); b0 += f.x; b1 += f.y;
            f = __half22float2(h[1]); b2 += f.x; b3 += f.y;
            h = (const __half2*)&v4;
            f = __half22float2(h[0]); a0 += f.x; a1 += f.y;
            f = __half22float2(h[1]); a2 += f.x; a3 += f.y;
            h = (const __half2*)&v5;
            f = __half22float2(h[0]); b0 += f.x; b1 += f.y;
            f = __half22float2(h[1]); b2 += f.x; b3 += f.y;
            h = (const __half2*)&v6;
            f = __half22float2(h[0]); a0 += f.x; a1 += f.y;
            f = __half22float2(h[1]); a2 += f.x; a3 += f.y;
            h = (const __half2*)&v7;
            f = __half22float2(h[0]); b0 += f.x; b1 += f.y;
            f = __half22float2(h[1]); b2 += f.x; b3 += f.y;
        }
        for (; j < cnt; ++j) {
            int s = (int)srt[st + j];
            uint2 v = *(const uint2*)(tmp + (size_t)s * OUT_F + 4 * c);
            const __half2* h = (const __half2*)&v;
            float2 f;
            if (j & 1) {
                f = __half22float2(h[0]); b0 += f.x; b1 += f.y;
                f = __half22float2(h[1]); b2 += f.x; b3 += f.y;
            } else {
                f = __half22float2(h[0]); a0 += f.x; a1 += f.y;
                f = __half22float2(h[1]); a2 += f.x; a3 += f.y;
            }
        }
        for (int e2 = 0; e2 < novf; ++e2) {        // ~always empty
            if (ovf[2 * e2 + 1] == node) {
                uint2 v = *(const uint2*)(tmp + (size_t)ovf[2 * e2] * OUT_F + 4 * c);
                const __half2* h = (const __half2*)&v;
                float2 f;
                f = __half22float2(h[0]); a0 += f.x; a1 += f.y;
                f = __half22float2(h[1]); a2 += f.x; a3 += f.y;
            }
        }

        float dg = (float)(cnt + in_cnt[node]);
        float sc = rsqrtf(fmaxf(dg, 1.0f));
        float4 o = make_float4((a0 + b0) * sc, (a1 + b1) * sc,
                               (a2 + b2) * sc, (a3 + b3) * sc);
        *(float4*)(out + (size_t)node * OUT_F + 4 * c) = o;
    }
}

// ---------------------------------------------------------------------------
// Fallback path (ws too small): degree + scaled-linear + atomic scatter.
// ---------------------------------------------------------------------------
__global__ void degree_kernel(const int* __restrict__ src, const int* __restrict__ dst,
                              int* __restrict__ out_cnt, int* __restrict__ in_cnt,
                              int n_edges) {
    int i = blockIdx.x * blockDim.x + threadIdx.x;
    if (i < n_edges) {
        atomicAdd(&out_cnt[src[i]], 1);
        atomicAdd(&in_cnt[dst[i]], 1);
    }
}

__global__ __launch_bounds__(256) void linear_fb(const float* __restrict__ feat,
                                                 const float* __restrict__ weight,
                                                 const int* __restrict__ out_cnt,
                                                 __half* __restrict__ tmp, int n_nodes) {
    __shared__ float w[IN_F * OUT_F];
    {
        const float4* wg = (const float4*)weight;
        float4* wsh = (float4*)w;
        for (int i = threadIdx.x; i < IN_F * OUT_F / 4; i += 256) wsh[i] = wg[i];
    }
    __syncthreads();
    int q  = threadIdx.x >> 3;
    int cg = threadIdx.x & 7;
    int row0 = blockIdx.x * 128 + q * 4;
    if (row0 >= n_nodes) return;
    int rmax = n_nodes - row0;
    if (rmax > 4) rmax = 4;
    const float4* feat4 = (const float4*)feat;
    float4 acc[4];
#pragma unroll
    for (int r = 0; r < 4; ++r) acc[r] = make_float4(0.f, 0.f, 0.f, 0.f);
    for (int k4 = 0; k4 < IN_F / 4; ++k4) {
        float4 wv0 = *(const float4*)&w[(4 * k4 + 0) * OUT_F + 4 * cg];
        float4 wv1 = *(const float4*)&w[(4 * k4 + 1) * OUT_F + 4 * cg];
        float4 wv2 = *(const float4*)&w[(4 * k4 + 2) * OUT_F + 4 * cg];
        float4 wv3 = *(const float4*)&w[(4 * k4 + 3) * OUT_F + 4 * cg];
#pragma unroll
        for (int r = 0; r < 4; ++r) {
            int rr = (r < rmax) ? r : 0;
            float4 f = feat4[(size_t)(row0 + rr) * (IN_F / 4) + k4];
            acc[r].x += f.x * wv0.x + f.y * wv1.x + f.z * wv2.x + f.w * wv3.x;
            acc[r].y += f.x * wv0.y + f.y * wv1.y + f.z * wv2.y + f.w * wv3.y;
            acc[r].z += f.x * wv0.z + f.y * wv1.z + f.z * wv2.z + f.w * wv3.z;
            acc[r].w += f.x * wv0.w + f.y * wv1.w + f.z * wv2.w + f.w * wv3.w;
        }
    }
#pragma unroll
    for (int r = 0; r < 4; ++r) {
        if (r < rmax) {
            float sc = rsqrtf(fmaxf((float)out_cnt[row0 + r], 1.0f));
            union { __half h[4]; uint2 u; } pk;
            pk.h[0] = __float2half(acc[r].x * sc);
            pk.h[1] = __float2half(acc[r].y * sc);
            pk.h[2] = __float2half(acc[r].z * sc);
            pk.h[3] = __float2half(acc[r].w * sc);
            *(uint2*)&tmp[(size_t)(row0 + r) * OUT_F + 4 * cg] = pk.u;
        }
    }
}

__global__ void scatter_kernel(const int* __restrict__ src, const int* __restrict__ dst,
                               const __half* __restrict__ tmp, float* __restrict__ out,
                               int n_edges) {
    long long t = (long long)blockIdx.x * blockDim.x + threadIdx.x;
    int e = (int)(t >> 5);
    int c = (int)(t & (OUT_F - 1));
    if (e < n_edges) {
        atomicAdd(&out[(size_t)dst[e] * OUT_F + c],
                  __half2float(tmp[(size_t)src[e] * OUT_F + c]));
    }
}

__global__ void finalize_kernel(float* __restrict__ out, const int* __restrict__ in_cnt,
                                int n_total) {
    int t = blockIdx.x * blockDim.x + threadIdx.x;
    if (t < n_total) {
        out[t] *= rsqrtf(fmaxf((float)in_cnt[t >> 5], 1.0f));
    }
}

extern "C" void kernel_launch(void* const* d_in, const int* in_sizes, int n_in,
                              void* d_out, int out_size, void* d_ws, size_t ws_size,
                              hipStream_t stream) {
    const float* feat   = (const float*)d_in[0];
    const int*   src    = (const int*)d_in[1];
    const int*   dst    = (const int*)d_in[2];
    const float* weight = (const float*)d_in[3];
    float*       out    = (float*)d_out;

    int n_nodes = in_sizes[0] / IN_F;   // 100000
    int n_edges = in_sizes[1];          // 1600000
    int n_buckets = (n_nodes + R_NODES - 1) / R_NODES;  // 391 (<= MAXNB)

    // ws layout: [out_cnt n][in_cnt n][gcur MAXNB][gcur2 MAXNB][ovf_cnt 8]
    //            [ovf 2*CAP][bkt nb*BKT_CAP u32][bkt2 nb*BKT2_CAP u16]
    //            [tmp fp16 n*32 (16B aligned)]
    int*      out_cnt = (int*)d_ws;
    int*      in_cnt  = out_cnt + n_nodes;
    int*      gcur    = in_cnt + n_nodes;
    int*      gcur2   = gcur + MAXNB;
    int*      ovf_cnt = gcur2 + MAXNB;
    int*      ovf     = ovf_cnt + 8;
    unsigned* bkt     = (unsigned*)(ovf + 2 * OVF_CAP);
    unsigned short* bkt2 = (unsigned short*)(bkt + (size_t)n_buckets * BKT_CAP);
    char*     tmp_raw = (char*)(bkt2 + (size_t)n_buckets * BKT2_CAP);
    __half*   tmp     = (__half*)(((uintptr_t)tmp_raw + 15) & ~(uintptr_t)15);
    size_t    needed  = (char*)(tmp + (size_t)n_nodes * OUT_F) - (char*)d_ws;

    if (ws_size >= needed && n_buckets <= MAXNB) {
        hipMemsetAsync(out_cnt, 0,
                       ((size_t)2 * n_nodes + 2 * MAXNB + 8) * sizeof(int), stream);
        int n_bbl = (n_edges + EPB - 1) / EPB;          // 196
        int n_lbl = (n_nodes + 511) / 512;              // 196
        mega_kernel<<<n_bbl + n_lbl, 1024, 0, stream>>>(
            src, dst, feat, weight, out_cnt, in_cnt, gcur, gcur2, bkt, bkt2,
            ovf, ovf_cnt, tmp, n_edges, n_nodes, n_bbl, n_lbl);
        scale_tmp<<<n_buckets, 256, 0, stream>>>(bkt2, gcur2, out_cnt, tmp, n_nodes);
        sortgather_kernel<<<n_buckets, 1024, 0, stream>>>(
            bkt, gcur, in_cnt, ovf, ovf_cnt, tmp, out, n_nodes);
    } else {
        // fallback: atomic scatter
        __half* tmp_fb = (__half*)(ovf + 2 * OVF_CAP);
        hipMemsetAsync(out_cnt, 0,
                       ((size_t)2 * n_nodes + 2 * MAXNB + 8) * sizeof(int), stream);
        hipMemsetAsync(d_out, 0, (size_t)out_size * sizeof(float), stream);
        degree_kernel<<<(n_edges + 255) / 256, 256, 0, stream>>>(src, dst, out_cnt, in_cnt, n_edges);
        linear_fb<<<(n_nodes + 127) / 128, 256, 0, stream>>>(feat, weight, out_cnt, tmp_fb, n_nodes);
        long long st = (long long)n_edges * OUT_F;
        scatter_kernel<<<(int)((st + 255) / 256), 256, 0, stream>>>(src, dst, tmp_fb, out, n_edges);
        finalize_kernel<<<(n_nodes * OUT_F + 255) / 256, 256, 0, stream>>>(out, in_cnt, n_nodes * OUT_F);
    }
}

// Round 4
// 188.716 us; speedup vs baseline: 1.1728x; 1.0300x over previous
//
#include <hip/hip_runtime.h>
#include <hip/hip_fp16.h>

#define IN_F 128
#define OUT_F 32
#define R_NODES 256          // dst nodes per bucket (8 bits)
#define RSHIFT 8
#define RMASK 255
#define BKT_CAP 7168         // dst buckets: Poisson(4092) + 16-pad (~5270 exp) + 9 sigma
#define BKT2_CAP 8192        // src buckets: 4092 + 32-pad*196 (~6580 exp) + sigma
#define OVF_CAP 4096
#define EPB 8192             // edges per build sub-block
#define MAXNB 512            // max buckets => n_nodes <= 131072
#define SENT 0xFFFFFFFFu     // pad sentinel in bkt (u32)
#define SENT2 0xFFFFu        // pad sentinel in bkt2 (u16)

// ---------------------------------------------------------------------------
// ROUND 4. Round-3 confirmed fabric-atomic theory (WRITE 66->21.5MB) but mega
// is still latency/barrier-bound (VALUBusy 15%, 5 sweeps, 8 barrier phases).
// Changes: (1) fuse D-hist+S-hist into ONE src+dst sweep (S-side hist/lbase/
// gbase live OUTSIDE the LDS union to survive phase D); (2) merge both
// prefix-scans into one phase; (3) int4-vectorize all edge sweeps (8 load
// rounds -> 2); (4) uint4-vectorize scale_tmp/sortgather bucket reads.
// Also: making mega cheaper than the back-half kernels forces sortgather/
// scale_tmp into next round's top-5 -> attribution for the ~120us pool.
// ---------------------------------------------------------------------------
struct BuildSmem {                   // phase D (dst sort)
    unsigned sorted[EPB];            // 32 KB
    unsigned short binof[EPB];       // 16 KB
    int hist[MAXNB];                 // count, then cursor
    int lbase[MAXNB];
    int gbase[MAXNB];
};
struct BuildSmemS {                  // phase S staging (aliases BuildSmem)
    unsigned short sorted[EPB];      // 16 KB (src & 255)
    unsigned short binof[EPB];       // 16 KB (src >> 8)
};
struct LinSmem { float w[IN_F * OUT_F]; };
union MegaSmem { BuildSmem b; BuildSmemS s; LinSmem l; };

__global__ __launch_bounds__(1024) void mega_kernel(
    const int* __restrict__ src, const int* __restrict__ dst,
    const float* __restrict__ feat, const float* __restrict__ weight,
    int* __restrict__ out_cnt, int* __restrict__ in_cnt,
    int* __restrict__ gcur, int* __restrict__ gcur2,
    unsigned* __restrict__ bkt, unsigned short* __restrict__ bkt2,
    int* __restrict__ ovf, int* __restrict__ ovf_cnt,
    __half* __restrict__ tmp, int n_edges, int n_nodes,
    int n_bbl, int n_lbl) {

    __shared__ MegaSmem sm;
    // phase-S state outside the union (must survive phase D's LDS reuse)
    __shared__ int shist[MAXNB];     // S histogram, then S cursor
    __shared__ int slbase[MAXNB];
    __shared__ int sgbase[MAXNB];
    __shared__ int wsumD[16], wsumS[16];

    int tid = threadIdx.x;
    int bid = blockIdx.x;

    // parity interleave: even -> build, odd -> linear (tail: whoever is left)
    int m2 = 2 * min(n_bbl, n_lbl);
    bool is_build;
    int sub;
    if (bid < m2) { is_build = ((bid & 1) == 0); sub = bid >> 1; }
    else          { is_build = (n_bbl > n_lbl);  sub = m2 / 2 + (bid - m2); }

    if (is_build) {
        int e0 = sub * EPB;
        int ecnt = min(EPB, n_edges - e0);
        int lane = tid & 63, wid = tid >> 6;
        int k4 = ecnt >> 2;
        const int4* src4 = (const int4*)(src + e0);
        const int4* dst4 = (const int4*)(dst + e0);

        // ========== fused hist sweep: BOTH histograms, one src+dst pass ====
        if (tid < MAXNB) { sm.b.hist[tid] = 0; shist[tid] = 0; }
        __syncthreads();

        for (int k = tid; k < k4; k += 1024) {
            int4 d4 = dst4[k];
            int4 s4 = src4[k];
            atomicAdd(&sm.b.hist[d4.x >> RSHIFT], 1);
            atomicAdd(&sm.b.hist[d4.y >> RSHIFT], 1);
            atomicAdd(&sm.b.hist[d4.z >> RSHIFT], 1);
            atomicAdd(&sm.b.hist[d4.w >> RSHIFT], 1);
            atomicAdd(&shist[s4.x >> RSHIFT], 1);
            atomicAdd(&shist[s4.y >> RSHIFT], 1);
            atomicAdd(&shist[s4.z >> RSHIFT], 1);
            atomicAdd(&shist[s4.w >> RSHIFT], 1);
        }
        for (int k = (k4 << 2) + tid; k < ecnt; k += 1024) {
            atomicAdd(&sm.b.hist[dst[e0 + k] >> RSHIFT], 1);
            atomicAdd(&shist[src[e0 + k] >> RSHIFT], 1);
        }
        __syncthreads();

        // ========== merged scans + chunk reserves (one phase) ==============
        int dcnt = (tid < MAXNB) ? sm.b.hist[tid] : 0;
        int scnt = (tid < MAXNB) ? shist[tid] : 0;
        int dscan = dcnt, sscan = scnt;
        for (int off = 1; off < 64; off <<= 1) {
            int v0 = __shfl_up(dscan, off, 64);
            int v1 = __shfl_up(sscan, off, 64);
            if (lane >= off) { dscan += v0; sscan += v1; }
        }
        if (lane == 63) { wsumD[wid] = dscan; wsumS[wid] = sscan; }
        __syncthreads();
        int woffD = 0, woffS = 0;
        for (int w = 0; w < wid; ++w) { woffD += wsumD[w]; woffS += wsumS[w]; }
        int exclD = woffD + dscan - dcnt;
        int exclS = woffS + sscan - scnt;
        if (tid < MAXNB) {
            sm.b.lbase[tid] = exclD;
            sm.b.hist[tid]  = exclD;        // D insertion cursor
            int resD = (dcnt + 15) & ~15;   // whole 64B lines (u32)
            if (dcnt > 0) sm.b.gbase[tid] = atomicAdd(&gcur[tid], resD);
            slbase[tid] = exclS;
            shist[tid]  = exclS;            // S insertion cursor
            int resS = (scnt + 31) & ~31;   // whole 64B lines (u16)
            if (scnt > 0) sgbase[tid] = atomicAdd(&gcur2[tid], resS);
        }
        __syncthreads();

        // ========== phase D sort: counting-sort into LDS (int4 loads) ======
        for (int k = tid; k < k4; k += 1024) {
            int4 s4 = src4[k];
            int4 d4 = dst4[k];
            int bin, idx;
            bin = d4.x >> RSHIFT; idx = atomicAdd(&sm.b.hist[bin], 1);
            sm.b.sorted[idx] = ((unsigned)s4.x << RSHIFT) | (unsigned)(d4.x & RMASK);
            sm.b.binof[idx] = (unsigned short)bin;
            bin = d4.y >> RSHIFT; idx = atomicAdd(&sm.b.hist[bin], 1);
            sm.b.sorted[idx] = ((unsigned)s4.y << RSHIFT) | (unsigned)(d4.y & RMASK);
            sm.b.binof[idx] = (unsigned short)bin;
            bin = d4.z >> RSHIFT; idx = atomicAdd(&sm.b.hist[bin], 1);
            sm.b.sorted[idx] = ((unsigned)s4.z << RSHIFT) | (unsigned)(d4.z & RMASK);
            sm.b.binof[idx] = (unsigned short)bin;
            bin = d4.w >> RSHIFT; idx = atomicAdd(&sm.b.hist[bin], 1);
            sm.b.sorted[idx] = ((unsigned)s4.w << RSHIFT) | (unsigned)(d4.w & RMASK);
            sm.b.binof[idx] = (unsigned short)bin;
        }
        for (int k = (k4 << 2) + tid; k < ecnt; k += 1024) {
            int s = src[e0 + k], d = dst[e0 + k];
            int bin = d >> RSHIFT;
            int idx = atomicAdd(&sm.b.hist[bin], 1);
            sm.b.sorted[idx] = ((unsigned)s << RSHIFT) | (unsigned)(d & RMASK);
            sm.b.binof[idx]  = (unsigned short)bin;
        }
        __syncthreads();

        // ========== phase D flush: dense line-aligned + sentinel pads ======
        for (int i = tid; i < ecnt; i += 1024) {
            unsigned v = sm.b.sorted[i];
            int bin = sm.b.binof[i];
            int gpos = sm.b.gbase[bin] + (i - sm.b.lbase[bin]);
            if (gpos < BKT_CAP) {
                bkt[(size_t)bin * BKT_CAP + gpos] = v;
            } else {
                int d = bin * R_NODES + (int)(v & RMASK);
                atomicAdd(&in_cnt[d], 1);   // overflow-only in-degree
                int o = atomicAdd(ovf_cnt, 1);
                if (o < OVF_CAP) {
                    ovf[2 * o]     = (int)(v >> RSHIFT);
                    ovf[2 * o + 1] = d;
                }
            }
        }
        for (int bin = tid; bin < MAXNB; bin += 1024) {
            int bc  = sm.b.hist[bin] - sm.b.lbase[bin];   // real count
            int res = (bc + 15) & ~15;
            for (int p = bc; p < res; ++p) {
                int gpos = sm.b.gbase[bin] + p;
                if (gpos < BKT_CAP) bkt[(size_t)bin * BKT_CAP + gpos] = SENT;
            }
        }
        __syncthreads();   // D staging LDS dead from here (S aliases it)

        // ========== phase S sort: src low-bytes into LDS (int4 loads) ======
        for (int k = tid; k < k4; k += 1024) {
            int4 s4 = src4[k];
            int bin, idx;
            bin = s4.x >> RSHIFT; idx = atomicAdd(&shist[bin], 1);
            sm.s.sorted[idx] = (unsigned short)(s4.x & RMASK);
            sm.s.binof[idx] = (unsigned short)bin;
            bin = s4.y >> RSHIFT; idx = atomicAdd(&shist[bin], 1);
            sm.s.sorted[idx] = (unsigned short)(s4.y & RMASK);
            sm.s.binof[idx] = (unsigned short)bin;
            bin = s4.z >> RSHIFT; idx = atomicAdd(&shist[bin], 1);
            sm.s.sorted[idx] = (unsigned short)(s4.z & RMASK);
            sm.s.binof[idx] = (unsigned short)bin;
            bin = s4.w >> RSHIFT; idx = atomicAdd(&shist[bin], 1);
            sm.s.sorted[idx] = (unsigned short)(s4.w & RMASK);
            sm.s.binof[idx] = (unsigned short)bin;
        }
        for (int k = (k4 << 2) + tid; k < ecnt; k += 1024) {
            int s = src[e0 + k];
            int bin = s >> RSHIFT;
            int idx = atomicAdd(&shist[bin], 1);
            sm.s.sorted[idx] = (unsigned short)(s & RMASK);
            sm.s.binof[idx]  = (unsigned short)bin;
        }
        __syncthreads();

        // ========== phase S flush ==========================================
        for (int i = tid; i < ecnt; i += 1024) {
            unsigned short v = sm.s.sorted[i];
            int bin = sm.s.binof[i];
            int gpos = sgbase[bin] + (i - slbase[bin]);
            if (gpos < BKT2_CAP) {
                bkt2[(size_t)bin * BKT2_CAP + gpos] = v;
            } else {
                atomicAdd(&out_cnt[bin * R_NODES + (int)v], 1);  // rare
            }
        }
        for (int bin = tid; bin < MAXNB; bin += 1024) {
            int bc  = shist[bin] - slbase[bin];
            int res = (bc + 31) & ~31;
            for (int p = bc; p < res; ++p) {
                int gpos = sgbase[bin] + p;
                if (gpos < BKT2_CAP) bkt2[(size_t)bin * BKT2_CAP + gpos] = SENT2;
            }
        }
    } else {
        // ===== linear: tmp(fp16) = feat @ W, UNSCALED =====
        if (tid < 1024) ((float4*)sm.l.w)[tid] = ((const float4*)weight)[tid];
        __syncthreads();

        int q  = tid >> 3;                  // 0..127 row-quads
        int cg = tid & 7;                   // col group of 4
        int row0 = sub * 512 + q * 4;
        if (row0 >= n_nodes) return;
        int rmax = n_nodes - row0;
        if (rmax > 4) rmax = 4;

        const float4* feat4 = (const float4*)feat;
        float4 acc[4];
#pragma unroll
        for (int r = 0; r < 4; ++r) acc[r] = make_float4(0.f, 0.f, 0.f, 0.f);

        for (int k4i = 0; k4i < IN_F / 4; ++k4i) {
            float4 wv0 = *(const float4*)&sm.l.w[(4 * k4i + 0) * OUT_F + 4 * cg];
            float4 wv1 = *(const float4*)&sm.l.w[(4 * k4i + 1) * OUT_F + 4 * cg];
            float4 wv2 = *(const float4*)&sm.l.w[(4 * k4i + 2) * OUT_F + 4 * cg];
            float4 wv3 = *(const float4*)&sm.l.w[(4 * k4i + 3) * OUT_F + 4 * cg];
#pragma unroll
            for (int r = 0; r < 4; ++r) {
                int rr = (r < rmax) ? r : 0;
                float4 f = feat4[(size_t)(row0 + rr) * (IN_F / 4) + k4i];
                acc[r].x += f.x * wv0.x + f.y * wv1.x + f.z * wv2.x + f.w * wv3.x;
                acc[r].y += f.x * wv0.y + f.y * wv1.y + f.z * wv2.y + f.w * wv3.y;
                acc[r].z += f.x * wv0.z + f.y * wv1.z + f.z * wv2.z + f.w * wv3.z;
                acc[r].w += f.x * wv0.w + f.y * wv1.w + f.z * wv2.w + f.w * wv3.w;
            }
        }

#pragma unroll
        for (int r = 0; r < 4; ++r) {
            if (r < rmax) {
                union { __half h[4]; uint2 u; } pk;
                pk.h[0] = __float2half(acc[r].x);
                pk.h[1] = __float2half(acc[r].y);
                pk.h[2] = __float2half(acc[r].z);
                pk.h[3] = __float2half(acc[r].w);
                *(uint2*)&tmp[(size_t)(row0 + r) * OUT_F + 4 * cg] = pk.u;
            }
        }
    }
}

// ---------------------------------------------------------------------------
// scale_tmp: one block per src-bucket. uint4 bkt2 reads (8 entries/load),
// LDS-histogram low-bytes -> out-degree -> fold rsqrt scale into tmp.
// ---------------------------------------------------------------------------
__global__ __launch_bounds__(256) void scale_tmp(
    const unsigned short* __restrict__ bkt2, const int* __restrict__ gcur2,
    const int* __restrict__ out_cnt, __half* __restrict__ tmp, int n_nodes) {
    __shared__ int hist[R_NODES];
    __shared__ float scf[R_NODES];
    int b = blockIdx.x, tid = threadIdx.x;

    hist[tid] = 0;
    __syncthreads();

    int ecnt = min(gcur2[b], BKT2_CAP);     // multiple of 32 entries
    const uint4* gb4 = (const uint4*)(bkt2 + (size_t)b * BKT2_CAP);
    int n4 = ecnt >> 3;                     // 8 u16 entries per uint4
    for (int i = tid; i < n4; i += 256) {
        uint4 v = gb4[i];
        unsigned e;
        e = v.x & 0xFFFF; if (e != SENT2) atomicAdd(&hist[e], 1);
        e = v.x >> 16;    if (e != SENT2) atomicAdd(&hist[e], 1);
        e = v.y & 0xFFFF; if (e != SENT2) atomicAdd(&hist[e], 1);
        e = v.y >> 16;    if (e != SENT2) atomicAdd(&hist[e], 1);
        e = v.z & 0xFFFF; if (e != SENT2) atomicAdd(&hist[e], 1);
        e = v.z >> 16;    if (e != SENT2) atomicAdd(&hist[e], 1);
        e = v.w & 0xFFFF; if (e != SENT2) atomicAdd(&hist[e], 1);
        e = v.w >> 16;    if (e != SENT2) atomicAdd(&hist[e], 1);
    }
    __syncthreads();

    int node = b * R_NODES + tid;
    if (node < n_nodes) {
        int deg = hist[tid] + out_cnt[node];   // overflow adds, usually 0
        scf[tid] = rsqrtf(fmaxf((float)deg, 1.0f));
    }
    __syncthreads();

#pragma unroll
    for (int p = 0; p < 4; ++p) {
        int r = p * 64 + (tid >> 2);
        int nd = b * R_NODES + r;
        if (nd >= n_nodes) continue;
        float sc = scf[r];
        uint4* ptr = (uint4*)(tmp + (size_t)nd * OUT_F) + (tid & 3);
        uint4 v = *ptr;
        __half2* h = (__half2*)&v;
#pragma unroll
        for (int i = 0; i < 4; ++i) {
            float2 f = __half22float2(h[i]);
            f.x *= sc; f.y *= sc;
            h[i] = __float22half2_rn(f);
        }
        *ptr = v;
    }
}

// ---------------------------------------------------------------------------
// Fused sort+gather+overflow: one 1024-thread block per 256-node bucket.
// uint4 bkt load; gather 8 lanes x 8B (uint2), 8-edge batches, float4 store.
// ---------------------------------------------------------------------------
__global__ __launch_bounds__(1024) void sortgather_kernel(
    const unsigned* __restrict__ bkt, const int* __restrict__ gcur,
    const int* __restrict__ in_cnt,
    const int* __restrict__ ovf, const int* __restrict__ ovf_cnt,
    const __half* __restrict__ tmp, float* __restrict__ out, int n_nodes) {

    __shared__ __align__(16) unsigned ent[BKT_CAP];   // 28 KB
    __shared__ unsigned srt[BKT_CAP];                 // 28 KB
    __shared__ int hist[R_NODES];
    __shared__ int base[R_NODES];
    __shared__ int start[R_NODES];

    int b = blockIdx.x, tid = threadIdx.x;
    int ecnt = min(gcur[b], BKT_CAP);       // multiple of 16 entries
    const unsigned* gb = bkt + (size_t)b * BKT_CAP;

    if (tid < R_NODES) hist[tid] = 0;
    __syncthreads();

    {
        const uint4* gb4 = (const uint4*)gb;
        int n4 = ecnt >> 2;
        for (int i = tid; i < n4; i += 1024) {
            uint4 v = gb4[i];
            ((uint4*)ent)[i] = v;
            if (v.x != SENT) atomicAdd(&hist[v.x & RMASK], 1);
            if (v.y != SENT) atomicAdd(&hist[v.y & RMASK], 1);
            if (v.z != SENT) atomicAdd(&hist[v.z & RMASK], 1);
            if (v.w != SENT) atomicAdd(&hist[v.w & RMASK], 1);
        }
    }
    __syncthreads();

    if (tid < 64) {                      // scan 256 bins, 4/lane
        int a0 = hist[4 * tid], a1 = hist[4 * tid + 1];
        int a2 = hist[4 * tid + 2], a3 = hist[4 * tid + 3];
        int s = a0 + a1 + a2 + a3;
        int sc = s;
        for (int off = 1; off < 64; off <<= 1) {
            int v = __shfl_up(sc, off, 64);
            if (tid >= off) sc += v;
        }
        int excl = sc - s;
        base[4 * tid]     = excl;
        base[4 * tid + 1] = excl + a0;
        base[4 * tid + 2] = excl + a0 + a1;
        base[4 * tid + 3] = excl + a0 + a1 + a2;
    }
    __syncthreads();
    if (tid < R_NODES) start[tid] = base[tid];
    __syncthreads();

    for (int i = tid; i < ecnt; i += 1024) {
        unsigned v = ent[i];
        if (v != SENT) {
            int p = atomicAdd(&base[v & RMASK], 1);
            srt[p] = v >> RSHIFT;        // src only
        }
    }
    __syncthreads();

    int g = tid >> 3;                    // group 0..127 (one node each pass)
    int c = tid & 7;                     // uint2 (4-half) column group
    int n0 = b * R_NODES;
    int novf = min(*ovf_cnt, OVF_CAP);

    for (int ln = g; ln < R_NODES; ln += 128) {
        int node = n0 + ln;
        if (node >= n_nodes) continue;
        int cnt = hist[ln];
        int st  = start[ln];

        float a0 = 0.f, a1 = 0.f, a2 = 0.f, a3 = 0.f;
        float b0 = 0.f, b1 = 0.f, b2 = 0.f, b3 = 0.f;
        int j = 0;
        for (; j + 8 <= cnt; j += 8) {
            int s0 = (int)srt[st + j + 0], s1 = (int)srt[st + j + 1];
            int s2 = (int)srt[st + j + 2], s3 = (int)srt[st + j + 3];
            int s4 = (int)srt[st + j + 4], s5 = (int)srt[st + j + 5];
            int s6 = (int)srt[st + j + 6], s7 = (int)srt[st + j + 7];
            uint2 v0 = *(const uint2*)(tmp + (size_t)s0 * OUT_F + 4 * c);
            uint2 v1 = *(const uint2*)(tmp + (size_t)s1 * OUT_F + 4 * c);
            uint2 v2 = *(const uint2*)(tmp + (size_t)s2 * OUT_F + 4 * c);
            uint2 v3 = *(const uint2*)(tmp + (size_t)s3 * OUT_F + 4 * c);
            uint2 v4 = *(const uint2*)(tmp + (size_t)s4 * OUT_F + 4 * c);
            uint2 v5 = *(const uint2*)(tmp + (size_t)s5 * OUT_F + 4 * c);
            uint2 v6 = *(const uint2*)(tmp + (size_t)s6 * OUT_F + 4 * c);
            uint2 v7 = *(const uint2*)(tmp + (size_t)s7 * OUT_F + 4 * c);
            const __half2* h;
            float2 f;
            h = (const __half2*)&v0;
            f = __half22float2(h[0]); a0 += f.x; a1 += f.y;
            f = __half22float2(h[1]); a2 += f.x; a3 += f.y;
            h = (const __half2*)&v1;
            f = __half22float2(h[0]); b0 += f.x; b1 += f.y;
            f = __half22float2(h[1]); b2 += f.x; b3 += f.y;
            h = (const __half2*)&v2;
            f = __half22float2(h[0]); a0 += f.x; a1 += f.y;
            f = __half22float2(h[1]); a2 += f.x; a3 += f.y;
            h = (const __half2*)&v3;
            f = __half22float2(h[0]); b0 += f.x; b1 += f.y;
            f = __half22float2(h[1]); b2 += f.x; b3 += f.y;
            h = (const __half2*)&v4;
            f = __half22float2(h[0]); a0 += f.x; a1 += f.y;
            f = __half22float2(h[1]); a2 += f.x; a3 += f.y;
            h = (const __half2*)&v5;
            f = __half22float2(h[0]); b0 += f.x; b1 += f.y;
            f = __half22float2(h[1]); b2 += f.x; b3 += f.y;
            h = (const __half2*)&v6;
            f = __half22float2(h[0]); a0 += f.x; a1 += f.y;
            f = __half22float2(h[1]); a2 += f.x; a3 += f.y;
            h = (const __half2*)&v7;
            f = __half22float2(h[0]); b0 += f.x; b1 += f.y;
            f = __half22float2(h[1]); b2 += f.x; b3 += f.y;
        }
        for (; j < cnt; ++j) {
            int s = (int)srt[st + j];
            uint2 v = *(const uint2*)(tmp + (size_t)s * OUT_F + 4 * c);
            const __half2* h = (const __half2*)&v;
            float2 f;
            if (j & 1) {
                f = __half22float2(h[0]); b0 += f.x; b1 += f.y;
                f = __half22float2(h[1]); b2 += f.x; b3 += f.y;
            } else {
                f = __half22float2(h[0]); a0 += f.x; a1 += f.y;
                f = __half22float2(h[1]); a2 += f.x; a3 += f.y;
            }
        }
        for (int e2 = 0; e2 < novf; ++e2) {        // ~always empty
            if (ovf[2 * e2 + 1] == node) {
                uint2 v = *(const uint2*)(tmp + (size_t)ovf[2 * e2] * OUT_F + 4 * c);
                const __half2* h = (const __half2*)&v;
                float2 f;
                f = __half22float2(h[0]); a0 += f.x; a1 += f.y;
                f = __half22float2(h[1]); a2 += f.x; a3 += f.y;
            }
        }

        float dg = (float)(cnt + in_cnt[node]);
        float sc = rsqrtf(fmaxf(dg, 1.0f));
        float4 o = make_float4((a0 + b0) * sc, (a1 + b1) * sc,
                               (a2 + b2) * sc, (a3 + b3) * sc);
        *(float4*)(out + (size_t)node * OUT_F + 4 * c) = o;
    }
}

// ---------------------------------------------------------------------------
// Fallback path (ws too small): degree + scaled-linear + atomic scatter.
// ---------------------------------------------------------------------------
__global__ void degree_kernel(const int* __restrict__ src, const int* __restrict__ dst,
                              int* __restrict__ out_cnt, int* __restrict__ in_cnt,
                              int n_edges) {
    int i = blockIdx.x * blockDim.x + threadIdx.x;
    if (i < n_edges) {
        atomicAdd(&out_cnt[src[i]], 1);
        atomicAdd(&in_cnt[dst[i]], 1);
    }
}

__global__ __launch_bounds__(256) void linear_fb(const float* __restrict__ feat,
                                                 const float* __restrict__ weight,
                                                 const int* __restrict__ out_cnt,
                                                 __half* __restrict__ tmp, int n_nodes) {
    __shared__ float w[IN_F * OUT_F];
    {
        const float4* wg = (const float4*)weight;
        float4* wsh = (float4*)w;
        for (int i = threadIdx.x; i < IN_F * OUT_F / 4; i += 256) wsh[i] = wg[i];
    }
    __syncthreads();
    int q  = threadIdx.x >> 3;
    int cg = threadIdx.x & 7;
    int row0 = blockIdx.x * 128 + q * 4;
    if (row0 >= n_nodes) return;
    int rmax = n_nodes - row0;
    if (rmax > 4) rmax = 4;
    const float4* feat4 = (const float4*)feat;
    float4 acc[4];
#pragma unroll
    for (int r = 0; r < 4; ++r) acc[r] = make_float4(0.f, 0.f, 0.f, 0.f);
    for (int k4 = 0; k4 < IN_F / 4; ++k4) {
        float4 wv0 = *(const float4*)&w[(4 * k4 + 0) * OUT_F + 4 * cg];
        float4 wv1 = *(const float4*)&w[(4 * k4 + 1) * OUT_F + 4 * cg];
        float4 wv2 = *(const float4*)&w[(4 * k4 + 2) * OUT_F + 4 * cg];
        float4 wv3 = *(const float4*)&w[(4 * k4 + 3) * OUT_F + 4 * cg];
#pragma unroll
        for (int r = 0; r < 4; ++r) {
            int rr = (r < rmax) ? r : 0;
            float4 f = feat4[(size_t)(row0 + rr) * (IN_F / 4) + k4];
            acc[r].x += f.x * wv0.x + f.y * wv1.x + f.z * wv2.x + f.w * wv3.x;
            acc[r].y += f.x * wv0.y + f.y * wv1.y + f.z * wv2.y + f.w * wv3.y;
            acc[r].z += f.x * wv0.z + f.y * wv1.z + f.z * wv2.z + f.w * wv3.z;
            acc[r].w += f.x * wv0.w + f.y * wv1.w + f.z * wv2.w + f.w * wv3.w;
        }
    }
#pragma unroll
    for (int r = 0; r < 4; ++r) {
        if (r < rmax) {
            float sc = rsqrtf(fmaxf((float)out_cnt[row0 + r], 1.0f));
            union { __half h[4]; uint2 u; } pk;
            pk.h[0] = __float2half(acc[r].x * sc);
            pk.h[1] = __float2half(acc[r].y * sc);
            pk.h[2] = __float2half(acc[r].z * sc);
            pk.h[3] = __float2half(acc[r].w * sc);
            *(uint2*)&tmp[(size_t)(row0 + r) * OUT_F + 4 * cg] = pk.u;
        }
    }
}

__global__ void scatter_kernel(const int* __restrict__ src, const int* __restrict__ dst,
                               const __half* __restrict__ tmp, float* __restrict__ out,
                               int n_edges) {
    long long t = (long long)blockIdx.x * blockDim.x + threadIdx.x;
    int e = (int)(t >> 5);
    int c = (int)(t & (OUT_F - 1));
    if (e < n_edges) {
        atomicAdd(&out[(size_t)dst[e] * OUT_F + c],
                  __half2float(tmp[(size_t)src[e] * OUT_F + c]));
    }
}

__global__ void finalize_kernel(float* __restrict__ out, const int* __restrict__ in_cnt,
                                int n_total) {
    int t = blockIdx.x * blockDim.x + threadIdx.x;
    if (t < n_total) {
        out[t] *= rsqrtf(fmaxf((float)in_cnt[t >> 5], 1.0f));
    }
}

extern "C" void kernel_launch(void* const* d_in, const int* in_sizes, int n_in,
                              void* d_out, int out_size, void* d_ws, size_t ws_size,
                              hipStream_t stream) {
    const float* feat   = (const float*)d_in[0];
    const int*   src    = (const int*)d_in[1];
    const int*   dst    = (const int*)d_in[2];
    const float* weight = (const float*)d_in[3];
    float*       out    = (float*)d_out;

    int n_nodes = in_sizes[0] / IN_F;   // 100000
    int n_edges = in_sizes[1];          // 1600000
    int n_buckets = (n_nodes + R_NODES - 1) / R_NODES;  // 391 (<= MAXNB)

    // ws layout: [out_cnt n][in_cnt n][gcur MAXNB][gcur2 MAXNB][ovf_cnt 8]
    //            [ovf 2*CAP][bkt nb*BKT_CAP u32][bkt2 nb*BKT2_CAP u16]
    //            [tmp fp16 n*32 (16B aligned)]
    int*      out_cnt = (int*)d_ws;
    int*      in_cnt  = out_cnt + n_nodes;
    int*      gcur    = in_cnt + n_nodes;
    int*      gcur2   = gcur + MAXNB;
    int*      ovf_cnt = gcur2 + MAXNB;
    int*      ovf     = ovf_cnt + 8;
    unsigned* bkt     = (unsigned*)(ovf + 2 * OVF_CAP);
    unsigned short* bkt2 = (unsigned short*)(bkt + (size_t)n_buckets * BKT_CAP);
    char*     tmp_raw = (char*)(bkt2 + (size_t)n_buckets * BKT2_CAP);
    __half*   tmp     = (__half*)(((uintptr_t)tmp_raw + 15) & ~(uintptr_t)15);
    size_t    needed  = (char*)(tmp + (size_t)n_nodes * OUT_F) - (char*)d_ws;

    if (ws_size >= needed && n_buckets <= MAXNB) {
        hipMemsetAsync(out_cnt, 0,
                       ((size_t)2 * n_nodes + 2 * MAXNB + 8) * sizeof(int), stream);
        int n_bbl = (n_edges + EPB - 1) / EPB;          // 196
        int n_lbl = (n_nodes + 511) / 512;              // 196
        mega_kernel<<<n_bbl + n_lbl, 1024, 0, stream>>>(
            src, dst, feat, weight, out_cnt, in_cnt, gcur, gcur2, bkt, bkt2,
            ovf, ovf_cnt, tmp, n_edges, n_nodes, n_bbl, n_lbl);
        scale_tmp<<<n_buckets, 256, 0, stream>>>(bkt2, gcur2, out_cnt, tmp, n_nodes);
        sortgather_kernel<<<n_buckets, 1024, 0, stream>>>(
            bkt, gcur, in_cnt, ovf, ovf_cnt, tmp, out, n_nodes);
    } else {
        // fallback: atomic scatter
        __half* tmp_fb = (__half*)(ovf + 2 * OVF_CAP);
        hipMemsetAsync(out_cnt, 0,
                       ((size_t)2 * n_nodes + 2 * MAXNB + 8) * sizeof(int), stream);
        hipMemsetAsync(d_out, 0, (size_t)out_size * sizeof(float), stream);
        degree_kernel<<<(n_edges + 255) / 256, 256, 0, stream>>>(src, dst, out_cnt, in_cnt, n_edges);
        linear_fb<<<(n_nodes + 127) / 128, 256, 0, stream>>>(feat, weight, out_cnt, tmp_fb, n_nodes);
        long long st = (long long)n_edges * OUT_F;
        scatter_kernel<<<(int)((st + 255) / 256), 256, 0, stream>>>(src, dst, tmp_fb, out, n_edges);
        finalize_kernel<<<(n_nodes * OUT_F + 255) / 256, 256, 0, stream>>>(out, in_cnt, n_nodes * OUT_F);
    }
}

// Round 5
// 183.907 us; speedup vs baseline: 1.2034x; 1.0261x over previous
//
#include <hip/hip_runtime.h>
#include <hip/hip_fp16.h>

#define IN_F 128
#define OUT_F 32
#define R_NODES 256          // dst nodes per bucket (8 bits)
#define RSHIFT 8
#define RMASK 255
#define OVF_CAP 4096
#define EPB 8192             // edges per build sub-block
#define MAXNB 512            // max bins => n_nodes <= 131072
#define MAXBBL 256           // max build blocks => n_edges <= 2.09M
#define C_D 40               // dst chunk cap: P(Poisson(21)>40) ~ 5e-5 per chunk
#define C_S 32               // src chunk cap: overflow -> fabric atomic (rare)
#define SRT_CAP 6144         // per-bucket sorted-src LDS cap (mean 4092, 32 sigma)

// ---------------------------------------------------------------------------
// ROUND 5. Round-4 falsifier fired: sweep fusion + int4 = null -> the LDS
// counting-sort machinery itself (32K LDS atomics/block, 3 edge passes,
// 7 barrier phases, 60.5KB LDS => 2 blocks/CU) is mega's cost. This round
// DELETES the sort: fixed-capacity per-(block,bin) chunks in a static global
// grid, written directly per edge with one LDS cursor atomic. Exact counts
// flow via cnts[bin][block] (no sentinels, no gcur, no prefix scan, no
// flush). Build: 1 pass, 2 LDS atomics/edge, 3 barriers, 4KB LDS.
// Downstream kernels use count-based validity.
// ---------------------------------------------------------------------------
struct BuildSmem { int dcur[MAXNB]; int scur[MAXNB]; };  // 4 KB
struct LinSmem { float w[IN_F * OUT_F]; };               // 16 KB
union MegaSmem { BuildSmem b; LinSmem l; };

__global__ __launch_bounds__(512) void mega_kernel(
    const int* __restrict__ src, const int* __restrict__ dst,
    const float* __restrict__ feat, const float* __restrict__ weight,
    int* __restrict__ out_cnt, int* __restrict__ in_cnt,
    unsigned* __restrict__ bkt, unsigned short* __restrict__ bkt2,
    unsigned short* __restrict__ cnts_d, unsigned short* __restrict__ cnts_s,
    int* __restrict__ ovf, int* __restrict__ ovf_cnt,
    __half* __restrict__ tmp, int n_edges, int n_nodes,
    int n_bbl, int n_lbl) {

    __shared__ MegaSmem sm;
    int tid = threadIdx.x;
    int bid = blockIdx.x;

    // interleave: every 3rd block is build (n_lbl ~= 2*n_bbl)
    int t = bid / 3, r = bid - 3 * t;
    bool is_build = (r == 0) && (t < n_bbl);
    int sub;
    if (is_build) sub = t;
    else {
        sub = bid - min(t + (r ? 1 : 0), n_bbl);
        if (sub >= n_lbl) return;
    }

    if (is_build) {
        int e0 = sub * EPB;
        int ecnt = min(EPB, n_edges - e0);
        int sD = n_bbl * C_D;            // u32 stride per dst bucket
        int sS = n_bbl * C_S;            // u16 stride per src bucket

        for (int i = tid; i < MAXNB; i += 512) {
            sm.b.dcur[i] = 0;
            sm.b.scur[i] = 0;
        }
        __syncthreads();

        int k4 = ecnt >> 2;
        const int4* src4 = (const int4*)(src + e0);
        const int4* dst4 = (const int4*)(dst + e0);

#define EDGE(ss, dd) {                                                        \
            int bin = (dd) >> RSHIFT;                                         \
            int idx = atomicAdd(&sm.b.dcur[bin], 1);                          \
            if (idx < C_D) {                                                  \
                bkt[(size_t)bin * sD + sub * C_D + idx] =                     \
                    ((unsigned)(ss) << RSHIFT) | (unsigned)((dd) & RMASK);    \
            } else {                                                          \
                atomicAdd(&in_cnt[dd], 1);                                    \
                int o = atomicAdd(ovf_cnt, 1);                                \
                if (o < OVF_CAP) { ovf[2 * o] = (ss); ovf[2 * o + 1] = (dd); }\
            }                                                                 \
            int b2 = (ss) >> RSHIFT;                                          \
            int i2 = atomicAdd(&sm.b.scur[b2], 1);                            \
            if (i2 < C_S) {                                                   \
                bkt2[(size_t)b2 * sS + sub * C_S + i2] =                      \
                    (unsigned short)((ss) & RMASK);                           \
            } else {                                                          \
                atomicAdd(&out_cnt[ss], 1);                                   \
            } }

        for (int k = tid; k < k4; k += 512) {
            int4 s4 = src4[k];
            int4 d4 = dst4[k];
            EDGE(s4.x, d4.x)
            EDGE(s4.y, d4.y)
            EDGE(s4.z, d4.z)
            EDGE(s4.w, d4.w)
        }
        for (int k = (k4 << 2) + tid; k < ecnt; k += 512) {
            int s = src[e0 + k], d = dst[e0 + k];
            EDGE(s, d)
        }
#undef EDGE
        __syncthreads();

        // publish exact per-(bin,block) counts
        for (int bin = tid; bin < MAXNB; bin += 512) {
            cnts_d[bin * MAXBBL + sub] = (unsigned short)min(sm.b.dcur[bin], C_D);
            cnts_s[bin * MAXBBL + sub] = (unsigned short)min(sm.b.scur[bin], C_S);
        }
    } else {
        // ===== linear: tmp(fp16) = feat @ W, UNSCALED (256 rows/block) =====
        for (int i = tid; i < IN_F * OUT_F / 4; i += 512)
            ((float4*)sm.l.w)[i] = ((const float4*)weight)[i];
        __syncthreads();

        int q  = tid >> 3;                  // 0..63 row-quads
        int cg = tid & 7;                   // col group of 4
        int row0 = sub * 256 + q * 4;
        if (row0 >= n_nodes) return;
        int rmax = n_nodes - row0;
        if (rmax > 4) rmax = 4;

        const float4* feat4 = (const float4*)feat;
        float4 acc[4];
#pragma unroll
        for (int rr = 0; rr < 4; ++rr) acc[rr] = make_float4(0.f, 0.f, 0.f, 0.f);

        for (int k4i = 0; k4i < IN_F / 4; ++k4i) {
            float4 wv0 = *(const float4*)&sm.l.w[(4 * k4i + 0) * OUT_F + 4 * cg];
            float4 wv1 = *(const float4*)&sm.l.w[(4 * k4i + 1) * OUT_F + 4 * cg];
            float4 wv2 = *(const float4*)&sm.l.w[(4 * k4i + 2) * OUT_F + 4 * cg];
            float4 wv3 = *(const float4*)&sm.l.w[(4 * k4i + 3) * OUT_F + 4 * cg];
#pragma unroll
            for (int rr = 0; rr < 4; ++rr) {
                int r2 = (rr < rmax) ? rr : 0;
                float4 f = feat4[(size_t)(row0 + r2) * (IN_F / 4) + k4i];
                acc[rr].x += f.x * wv0.x + f.y * wv1.x + f.z * wv2.x + f.w * wv3.x;
                acc[rr].y += f.x * wv0.y + f.y * wv1.y + f.z * wv2.y + f.w * wv3.y;
                acc[rr].z += f.x * wv0.z + f.y * wv1.z + f.z * wv2.z + f.w * wv3.z;
                acc[rr].w += f.x * wv0.w + f.y * wv1.w + f.z * wv2.w + f.w * wv3.w;
            }
        }

#pragma unroll
        for (int rr = 0; rr < 4; ++rr) {
            if (rr < rmax) {
                union { __half h[4]; uint2 u; } pk;
                pk.h[0] = __float2half(acc[rr].x);
                pk.h[1] = __float2half(acc[rr].y);
                pk.h[2] = __float2half(acc[rr].z);
                pk.h[3] = __float2half(acc[rr].w);
                *(uint2*)&tmp[(size_t)(row0 + rr) * OUT_F + 4 * cg] = pk.u;
            }
        }
    }
}

// ---------------------------------------------------------------------------
// scale_tmp: one 256-thr block per src-bucket. Scan fixed [n_bbl][C_S] u16
// grid with count-based validity (uint4 = 8 entries; C_S=32 -> no straddle),
// LDS-histogram low bytes -> out-degree -> fold rsqrt into tmp.
// ---------------------------------------------------------------------------
__global__ __launch_bounds__(256) void scale_tmp(
    const unsigned short* __restrict__ bkt2,
    const unsigned short* __restrict__ cnts_s,
    const int* __restrict__ out_cnt, __half* __restrict__ tmp,
    int n_nodes, int n_bbl) {
    __shared__ int hist[R_NODES];
    __shared__ float scf[R_NODES];
    __shared__ unsigned short cnt[MAXBBL];
    int b = blockIdx.x, tid = threadIdx.x;

    hist[tid] = 0;
    for (int i = tid; i < n_bbl; i += 256) cnt[i] = cnts_s[b * MAXBBL + i];
    __syncthreads();

    int sS = n_bbl * C_S;
    const uint4* g4 = (const uint4*)(bkt2 + (size_t)b * sS);
    int n4 = sS >> 3;                       // 8 u16 entries per uint4
    for (int i = tid; i < n4; i += 256) {
        int e0 = i << 3;
        int c = e0 >> 5;                    // C_S = 32
        int w = e0 & 31;
        int cc = cnt[c];
        if (w >= cc) continue;              // fully invalid oct
        uint4 v = g4[i];
        unsigned e;
        e = v.x & 0xFFFF;             atomicAdd(&hist[e], 1);
        e = v.x >> 16;    if (w + 1 < cc) atomicAdd(&hist[e], 1);
        e = v.y & 0xFFFF; if (w + 2 < cc) atomicAdd(&hist[e], 1);
        e = v.y >> 16;    if (w + 3 < cc) atomicAdd(&hist[e], 1);
        e = v.z & 0xFFFF; if (w + 4 < cc) atomicAdd(&hist[e], 1);
        e = v.z >> 16;    if (w + 5 < cc) atomicAdd(&hist[e], 1);
        e = v.w & 0xFFFF; if (w + 6 < cc) atomicAdd(&hist[e], 1);
        e = v.w >> 16;    if (w + 7 < cc) atomicAdd(&hist[e], 1);
    }
    __syncthreads();

    int node = b * R_NODES + tid;
    if (node < n_nodes) {
        int deg = hist[tid] + out_cnt[node];   // + rare overflow adds
        scf[tid] = rsqrtf(fmaxf((float)deg, 1.0f));
    }
    __syncthreads();

#pragma unroll
    for (int p = 0; p < 4; ++p) {
        int rr = p * 64 + (tid >> 2);
        int nd = b * R_NODES + rr;
        if (nd >= n_nodes) continue;
        float sc = scf[rr];
        uint4* ptr = (uint4*)(tmp + (size_t)nd * OUT_F) + (tid & 3);
        uint4 v = *ptr;
        __half2* h = (__half2*)&v;
#pragma unroll
        for (int i = 0; i < 4; ++i) {
            float2 f = __half22float2(h[i]);
            f.x *= sc; f.y *= sc;
            h[i] = __float22half2_rn(f);
        }
        *ptr = v;
    }
}

// ---------------------------------------------------------------------------
// sortgather: one 512-thr block per 256-node dst bucket. Two grid scans
// (hist, reorder) with count validity; no LDS staging of the grid; then the
// proven 8-lane x uint2 gather.
// ---------------------------------------------------------------------------
__global__ __launch_bounds__(512) void sortgather_kernel(
    const unsigned* __restrict__ bkt,
    const unsigned short* __restrict__ cnts_d,
    const int* __restrict__ in_cnt,
    const int* __restrict__ ovf, const int* __restrict__ ovf_cnt,
    const __half* __restrict__ tmp, float* __restrict__ out,
    int n_nodes, int n_bbl) {

    __shared__ unsigned srt[SRT_CAP];       // 24 KB (src ids, node-sorted)
    __shared__ unsigned short cnt[MAXBBL];
    __shared__ int hist[R_NODES];
    __shared__ int base[R_NODES];
    __shared__ int start[R_NODES];

    int b = blockIdx.x, tid = threadIdx.x;

    if (tid < R_NODES) hist[tid] = 0;
    for (int i = tid; i < n_bbl; i += 512) cnt[i] = cnts_d[b * MAXBBL + i];
    __syncthreads();

    int sD = n_bbl * C_D;
    const uint4* g4 = (const uint4*)(bkt + (size_t)b * sD);
    int n4 = sD >> 2;                       // 4 u32 entries per uint4 (4|C_D)

    for (int i = tid; i < n4; i += 512) {
        int e0 = i << 2;
        int c = e0 / C_D;                   // const-div -> magic mul
        int w = e0 - c * C_D;
        int cc = cnt[c];
        if (w >= cc) continue;
        uint4 v = g4[i];
        atomicAdd(&hist[v.x & RMASK], 1);
        if (w + 1 < cc) atomicAdd(&hist[v.y & RMASK], 1);
        if (w + 2 < cc) atomicAdd(&hist[v.z & RMASK], 1);
        if (w + 3 < cc) atomicAdd(&hist[v.w & RMASK], 1);
    }
    __syncthreads();

    if (tid < 64) {                      // scan 256 bins, 4/lane
        int a0 = hist[4 * tid], a1 = hist[4 * tid + 1];
        int a2 = hist[4 * tid + 2], a3 = hist[4 * tid + 3];
        int s = a0 + a1 + a2 + a3;
        int sc = s;
        for (int off = 1; off < 64; off <<= 1) {
            int v = __shfl_up(sc, off, 64);
            if (tid >= off) sc += v;
        }
        int excl = sc - s;
        base[4 * tid]     = excl;
        base[4 * tid + 1] = excl + a0;
        base[4 * tid + 2] = excl + a0 + a1;
        base[4 * tid + 3] = excl + a0 + a1 + a2;
    }
    __syncthreads();
    if (tid < R_NODES) start[tid] = base[tid];
    __syncthreads();

    for (int i = tid; i < n4; i += 512) {
        int e0 = i << 2;
        int c = e0 / C_D;
        int w = e0 - c * C_D;
        int cc = cnt[c];
        if (w >= cc) continue;
        uint4 v = g4[i];
        int p;
        p = atomicAdd(&base[v.x & RMASK], 1);
        if (p < SRT_CAP) srt[p] = v.x >> RSHIFT;
        if (w + 1 < cc) { p = atomicAdd(&base[v.y & RMASK], 1);
                          if (p < SRT_CAP) srt[p] = v.y >> RSHIFT; }
        if (w + 2 < cc) { p = atomicAdd(&base[v.z & RMASK], 1);
                          if (p < SRT_CAP) srt[p] = v.z >> RSHIFT; }
        if (w + 3 < cc) { p = atomicAdd(&base[v.w & RMASK], 1);
                          if (p < SRT_CAP) srt[p] = v.w >> RSHIFT; }
    }
    __syncthreads();

    int g = tid >> 3;                    // group 0..63
    int c = tid & 7;                     // uint2 (4-half) column group
    int n0 = b * R_NODES;
    int novf = min(*ovf_cnt, OVF_CAP);

    for (int ln = g; ln < R_NODES; ln += 64) {
        int node = n0 + ln;
        if (node >= n_nodes) continue;
        int cntn = hist[ln];
        int st   = start[ln];

        float a0 = 0.f, a1 = 0.f, a2 = 0.f, a3 = 0.f;
        float b0 = 0.f, b1 = 0.f, b2 = 0.f, b3 = 0.f;
        int j = 0;
        for (; j + 8 <= cntn; j += 8) {
            int s0 = (int)srt[st + j + 0], s1 = (int)srt[st + j + 1];
            int s2 = (int)srt[st + j + 2], s3 = (int)srt[st + j + 3];
            int s4 = (int)srt[st + j + 4], s5 = (int)srt[st + j + 5];
            int s6 = (int)srt[st + j + 6], s7 = (int)srt[st + j + 7];
            uint2 v0 = *(const uint2*)(tmp + (size_t)s0 * OUT_F + 4 * c);
            uint2 v1 = *(const uint2*)(tmp + (size_t)s1 * OUT_F + 4 * c);
            uint2 v2 = *(const uint2*)(tmp + (size_t)s2 * OUT_F + 4 * c);
            uint2 v3 = *(const uint2*)(tmp + (size_t)s3 * OUT_F + 4 * c);
            uint2 v4 = *(const uint2*)(tmp + (size_t)s4 * OUT_F + 4 * c);
            uint2 v5 = *(const uint2*)(tmp + (size_t)s5 * OUT_F + 4 * c);
            uint2 v6 = *(const uint2*)(tmp + (size_t)s6 * OUT_F + 4 * c);
            uint2 v7 = *(const uint2*)(tmp + (size_t)s7 * OUT_F + 4 * c);
            const __half2* h;
            float2 f;
            h = (const __half2*)&v0;
            f = __half22float2(h[0]); a0 += f.x; a1 += f.y;
            f = __half22float2(h[1]); a2 += f.x; a3 += f.y;
            h = (const __half2*)&v1;
            f = __half22float2(h[0]); b0 += f.x; b1 += f.y;
            f = __half22float2(h[1]); b2 += f.x; b3 += f.y;
            h = (const __half2*)&v2;
            f = __half22float2(h[0]); a0 += f.x; a1 += f.y;
            f = __half22float2(h[1]); a2 += f.x; a3 += f.y;
            h = (const __half2*)&v3;
            f = __half22float2(h[0]); b0 += f.x; b1 += f.y;
            f = __half22float2(h[1]); b2 += f.x; b3 += f.y;
            h = (const __half2*)&v4;
            f = __half22float2(h[0]); a0 += f.x; a1 += f.y;
            f = __half22float2(h[1]); a2 += f.x; a3 += f.y;
            h = (const __half2*)&v5;
            f = __half22float2(h[0]); b0 += f.x; b1 += f.y;
            f = __half22float2(h[1]); b2 += f.x; b3 += f.y;
            h = (const __half2*)&v6;
            f = __half22float2(h[0]); a0 += f.x; a1 += f.y;
            f = __half22float2(h[1]); a2 += f.x; a3 += f.y;
            h = (const __half2*)&v7;
            f = __half22float2(h[0]); b0 += f.x; b1 += f.y;
            f = __half22float2(h[1]); b2 += f.x; b3 += f.y;
        }
        for (; j < cntn; ++j) {
            int s = (int)srt[st + j];
            uint2 v = *(const uint2*)(tmp + (size_t)s * OUT_F + 4 * c);
            const __half2* h = (const __half2*)&v;
            float2 f;
            if (j & 1) {
                f = __half22float2(h[0]); b0 += f.x; b1 += f.y;
                f = __half22float2(h[1]); b2 += f.x; b3 += f.y;
            } else {
                f = __half22float2(h[0]); a0 += f.x; a1 += f.y;
                f = __half22float2(h[1]); a2 += f.x; a3 += f.y;
            }
        }
        for (int e2 = 0; e2 < novf; ++e2) {        // ~always empty
            if (ovf[2 * e2 + 1] == node) {
                uint2 v = *(const uint2*)(tmp + (size_t)ovf[2 * e2] * OUT_F + 4 * c);
                const __half2* h = (const __half2*)&v;
                float2 f;
                f = __half22float2(h[0]); a0 += f.x; a1 += f.y;
                f = __half22float2(h[1]); a2 += f.x; a3 += f.y;
            }
        }

        float dg = (float)(cntn + in_cnt[node]);
        float sc = rsqrtf(fmaxf(dg, 1.0f));
        float4 o = make_float4((a0 + b0) * sc, (a1 + b1) * sc,
                               (a2 + b2) * sc, (a3 + b3) * sc);
        *(float4*)(out + (size_t)node * OUT_F + 4 * c) = o;
    }
}

// ---------------------------------------------------------------------------
// Fallback path (ws too small): degree + scaled-linear + atomic scatter.
// ---------------------------------------------------------------------------
__global__ void degree_kernel(const int* __restrict__ src, const int* __restrict__ dst,
                              int* __restrict__ out_cnt, int* __restrict__ in_cnt,
                              int n_edges) {
    int i = blockIdx.x * blockDim.x + threadIdx.x;
    if (i < n_edges) {
        atomicAdd(&out_cnt[src[i]], 1);
        atomicAdd(&in_cnt[dst[i]], 1);
    }
}

__global__ __launch_bounds__(256) void linear_fb(const float* __restrict__ feat,
                                                 const float* __restrict__ weight,
                                                 const int* __restrict__ out_cnt,
                                                 __half* __restrict__ tmp, int n_nodes) {
    __shared__ float w[IN_F * OUT_F];
    {
        const float4* wg = (const float4*)weight;
        float4* wsh = (float4*)w;
        for (int i = threadIdx.x; i < IN_F * OUT_F / 4; i += 256) wsh[i] = wg[i];
    }
    __syncthreads();
    int q  = threadIdx.x >> 3;
    int cg = threadIdx.x & 7;
    int row0 = blockIdx.x * 128 + q * 4;
    if (row0 >= n_nodes) return;
    int rmax = n_nodes - row0;
    if (rmax > 4) rmax = 4;
    const float4* feat4 = (const float4*)feat;
    float4 acc[4];
#pragma unroll
    for (int r = 0; r < 4; ++r) acc[r] = make_float4(0.f, 0.f, 0.f, 0.f);
    for (int k4 = 0; k4 < IN_F / 4; ++k4) {
        float4 wv0 = *(const float4*)&w[(4 * k4 + 0) * OUT_F + 4 * cg];
        float4 wv1 = *(const float4*)&w[(4 * k4 + 1) * OUT_F + 4 * cg];
        float4 wv2 = *(const float4*)&w[(4 * k4 + 2) * OUT_F + 4 * cg];
        float4 wv3 = *(const float4*)&w[(4 * k4 + 3) * OUT_F + 4 * cg];
#pragma unroll
        for (int r = 0; r < 4; ++r) {
            int rr = (r < rmax) ? r : 0;
            float4 f = feat4[(size_t)(row0 + rr) * (IN_F / 4) + k4];
            acc[r].x += f.x * wv0.x + f.y * wv1.x + f.z * wv2.x + f.w * wv3.x;
            acc[r].y += f.x * wv0.y + f.y * wv1.y + f.z * wv2.y + f.w * wv3.y;
            acc[r].z += f.x * wv0.z + f.y * wv1.z + f.z * wv2.z + f.w * wv3.z;
            acc[r].w += f.x * wv0.w + f.y * wv1.w + f.z * wv2.w + f.w * wv3.w;
        }
    }
#pragma unroll
    for (int r = 0; r < 4; ++r) {
        if (r < rmax) {
            float sc = rsqrtf(fmaxf((float)out_cnt[row0 + r], 1.0f));
            union { __half h[4]; uint2 u; } pk;
            pk.h[0] = __float2half(acc[r].x * sc);
            pk.h[1] = __float2half(acc[r].y * sc);
            pk.h[2] = __float2half(acc[r].z * sc);
            pk.h[3] = __float2half(acc[r].w * sc);
            *(uint2*)&tmp[(size_t)(row0 + r) * OUT_F + 4 * cg] = pk.u;
        }
    }
}

__global__ void scatter_kernel(const int* __restrict__ src, const int* __restrict__ dst,
                               const __half* __restrict__ tmp, float* __restrict__ out,
                               int n_edges) {
    long long t = (long long)blockIdx.x * blockDim.x + threadIdx.x;
    int e = (int)(t >> 5);
    int c = (int)(t & (OUT_F - 1));
    if (e < n_edges) {
        atomicAdd(&out[(size_t)dst[e] * OUT_F + c],
                  __half2float(tmp[(size_t)src[e] * OUT_F + c]));
    }
}

__global__ void finalize_kernel(float* __restrict__ out, const int* __restrict__ in_cnt,
                                int n_total) {
    int t = blockIdx.x * blockDim.x + threadIdx.x;
    if (t < n_total) {
        out[t] *= rsqrtf(fmaxf((float)in_cnt[t >> 5], 1.0f));
    }
}

extern "C" void kernel_launch(void* const* d_in, const int* in_sizes, int n_in,
                              void* d_out, int out_size, void* d_ws, size_t ws_size,
                              hipStream_t stream) {
    const float* feat   = (const float*)d_in[0];
    const int*   src    = (const int*)d_in[1];
    const int*   dst    = (const int*)d_in[2];
    const float* weight = (const float*)d_in[3];
    float*       out    = (float*)d_out;

    int n_nodes = in_sizes[0] / IN_F;   // 100000
    int n_edges = in_sizes[1];          // 1600000
    int n_buckets = (n_nodes + R_NODES - 1) / R_NODES;  // 391
    int n_bbl = (n_edges + EPB - 1) / EPB;              // 196
    int n_lbl = (n_nodes + 255) / 256;                  // 391

    // ws layout: [out_cnt n][in_cnt n][ovf_cnt 8][ovf 2*CAP]
    //            [cnts_d MAXNB*MAXBBL u16][cnts_s same]
    //            [bkt nb x n_bbl*C_D u32][bkt2 nb x n_bbl*C_S u16][tmp]
    int*      out_cnt = (int*)d_ws;
    int*      in_cnt  = out_cnt + n_nodes;
    int*      ovf_cnt = in_cnt + n_nodes;
    int*      ovf     = ovf_cnt + 8;
    unsigned short* cnts_d = (unsigned short*)(ovf + 2 * OVF_CAP);
    unsigned short* cnts_s = cnts_d + (size_t)MAXNB * MAXBBL;
    char*     bkt_raw = (char*)(cnts_s + (size_t)MAXNB * MAXBBL);
    unsigned* bkt     = (unsigned*)(((uintptr_t)bkt_raw + 15) & ~(uintptr_t)15);
    int sD = n_bbl * C_D;
    int sS = n_bbl * C_S;
    unsigned short* bkt2 = (unsigned short*)(bkt + (size_t)n_buckets * sD);
    char*     tmp_raw = (char*)(bkt2 + (size_t)n_buckets * sS);
    __half*   tmp     = (__half*)(((uintptr_t)tmp_raw + 15) & ~(uintptr_t)15);
    size_t    needed  = (char*)(tmp + (size_t)n_nodes * OUT_F) - (char*)d_ws;

    if (ws_size >= needed && n_buckets <= MAXNB && n_bbl <= MAXBBL) {
        hipMemsetAsync(out_cnt, 0, ((size_t)2 * n_nodes + 8) * sizeof(int), stream);
        mega_kernel<<<n_bbl + n_lbl, 512, 0, stream>>>(
            src, dst, feat, weight, out_cnt, in_cnt, bkt, bkt2,
            cnts_d, cnts_s, ovf, ovf_cnt, tmp, n_edges, n_nodes, n_bbl, n_lbl);
        scale_tmp<<<n_buckets, 256, 0, stream>>>(
            bkt2, cnts_s, out_cnt, tmp, n_nodes, n_bbl);
        sortgather_kernel<<<n_buckets, 512, 0, stream>>>(
            bkt, cnts_d, in_cnt, ovf, ovf_cnt, tmp, out, n_nodes, n_bbl);
    } else {
        // fallback: atomic scatter
        __half* tmp_fb = (__half*)(ovf + 2 * OVF_CAP);
        hipMemsetAsync(out_cnt, 0, ((size_t)2 * n_nodes + 8) * sizeof(int), stream);
        hipMemsetAsync(d_out, 0, (size_t)out_size * sizeof(float), stream);
        degree_kernel<<<(n_edges + 255) / 256, 256, 0, stream>>>(src, dst, out_cnt, in_cnt, n_edges);
        linear_fb<<<(n_nodes + 127) / 128, 256, 0, stream>>>(feat, weight, out_cnt, tmp_fb, n_nodes);
        long long st = (long long)n_edges * OUT_F;
        scatter_kernel<<<(int)((st + 255) / 256), 256, 0, stream>>>(src, dst, tmp_fb, out, n_edges);
        finalize_kernel<<<(n_nodes * OUT_F + 255) / 256, 256, 0, stream>>>(out, in_cnt, n_nodes * OUT_F);
    }
}

// Round 6
// 182.035 us; speedup vs baseline: 1.2158x; 1.0103x over previous
//
#include <hip/hip_runtime.h>
#include <hip/hip_fp16.h>

#define IN_F 128
#define OUT_F 32
#define R_NODES 256          // dst nodes per bucket (8 bits)
#define RSHIFT 8
#define RMASK 255
#define OVF_CAP 4096
#define EPB 8192             // edges per build sub-block
#define MAXNB 512            // max bins => n_nodes <= 131072
#define MAXBBL 256           // max build blocks => n_edges <= 2.09M
#define C_D 40               // dst chunk cap: P(Poisson(21)>40) ~ 5e-5 per chunk
#define C_S 32               // src chunk cap: overflow -> fabric atomic (rare)
#define SRT_CAP 6144         // per-bucket sorted-src LDS cap (mean 4092)

// ---------------------------------------------------------------------------
// ROUND 6. Round-5 falsifier fired AGAIN: build w/o sort (1 pass, 2 LDS
// atomics/edge) = 75us = build w/ full sort = round-2 split build. Build is
// invariant to structure -> stop redesigning it (mega kept BIT-IDENTICAL).
// Cross-round arithmetic (total - mega = 109-124us in R1/R3/R4/R5; R1's
// scale_tmp was trivial => R1 sortgather ~= 105us) says SORTGATHER is the
// biggest kernel in the pipeline, hidden behind mega in top-5. This round:
// 2x wave-parallelism on the back half (sortgather 512->1024 thr, scale_tmp
// 256->512 thr) -> halves per-thread serial scan/gather chains, doubles
// outstanding loads. 391 blocks x 16 waves = 24 waves/CU for sortgather.
// ---------------------------------------------------------------------------
struct BuildSmem { int dcur[MAXNB]; int scur[MAXNB]; };  // 4 KB
struct LinSmem { float w[IN_F * OUT_F]; };               // 16 KB
union MegaSmem { BuildSmem b; LinSmem l; };

__global__ __launch_bounds__(512) void mega_kernel(
    const int* __restrict__ src, const int* __restrict__ dst,
    const float* __restrict__ feat, const float* __restrict__ weight,
    int* __restrict__ out_cnt, int* __restrict__ in_cnt,
    unsigned* __restrict__ bkt, unsigned short* __restrict__ bkt2,
    unsigned short* __restrict__ cnts_d, unsigned short* __restrict__ cnts_s,
    int* __restrict__ ovf, int* __restrict__ ovf_cnt,
    __half* __restrict__ tmp, int n_edges, int n_nodes,
    int n_bbl, int n_lbl) {

    __shared__ MegaSmem sm;
    int tid = threadIdx.x;
    int bid = blockIdx.x;

    // interleave: every 3rd block is build (n_lbl ~= 2*n_bbl)
    int t = bid / 3, r = bid - 3 * t;
    bool is_build = (r == 0) && (t < n_bbl);
    int sub;
    if (is_build) sub = t;
    else {
        sub = bid - min(t + (r ? 1 : 0), n_bbl);
        if (sub >= n_lbl) return;
    }

    if (is_build) {
        int e0 = sub * EPB;
        int ecnt = min(EPB, n_edges - e0);
        int sD = n_bbl * C_D;            // u32 stride per dst bucket
        int sS = n_bbl * C_S;            // u16 stride per src bucket

        for (int i = tid; i < MAXNB; i += 512) {
            sm.b.dcur[i] = 0;
            sm.b.scur[i] = 0;
        }
        __syncthreads();

        int k4 = ecnt >> 2;
        const int4* src4 = (const int4*)(src + e0);
        const int4* dst4 = (const int4*)(dst + e0);

#define EDGE(ss, dd) {                                                        \
            int bin = (dd) >> RSHIFT;                                         \
            int idx = atomicAdd(&sm.b.dcur[bin], 1);                          \
            if (idx < C_D) {                                                  \
                bkt[(size_t)bin * sD + sub * C_D + idx] =                     \
                    ((unsigned)(ss) << RSHIFT) | (unsigned)((dd) & RMASK);    \
            } else {                                                          \
                atomicAdd(&in_cnt[dd], 1);                                    \
                int o = atomicAdd(ovf_cnt, 1);                                \
                if (o < OVF_CAP) { ovf[2 * o] = (ss); ovf[2 * o + 1] = (dd); }\
            }                                                                 \
            int b2 = (ss) >> RSHIFT;                                          \
            int i2 = atomicAdd(&sm.b.scur[b2], 1);                            \
            if (i2 < C_S) {                                                   \
                bkt2[(size_t)b2 * sS + sub * C_S + i2] =                      \
                    (unsigned short)((ss) & RMASK);                           \
            } else {                                                          \
                atomicAdd(&out_cnt[ss], 1);                                   \
            } }

        for (int k = tid; k < k4; k += 512) {
            int4 s4 = src4[k];
            int4 d4 = dst4[k];
            EDGE(s4.x, d4.x)
            EDGE(s4.y, d4.y)
            EDGE(s4.z, d4.z)
            EDGE(s4.w, d4.w)
        }
        for (int k = (k4 << 2) + tid; k < ecnt; k += 512) {
            int s = src[e0 + k], d = dst[e0 + k];
            EDGE(s, d)
        }
#undef EDGE
        __syncthreads();

        // publish exact per-(bin,block) counts
        for (int bin = tid; bin < MAXNB; bin += 512) {
            cnts_d[bin * MAXBBL + sub] = (unsigned short)min(sm.b.dcur[bin], C_D);
            cnts_s[bin * MAXBBL + sub] = (unsigned short)min(sm.b.scur[bin], C_S);
        }
    } else {
        // ===== linear: tmp(fp16) = feat @ W, UNSCALED (256 rows/block) =====
        for (int i = tid; i < IN_F * OUT_F / 4; i += 512)
            ((float4*)sm.l.w)[i] = ((const float4*)weight)[i];
        __syncthreads();

        int q  = tid >> 3;                  // 0..63 row-quads
        int cg = tid & 7;                   // col group of 4
        int row0 = sub * 256 + q * 4;
        if (row0 >= n_nodes) return;
        int rmax = n_nodes - row0;
        if (rmax > 4) rmax = 4;

        const float4* feat4 = (const float4*)feat;
        float4 acc[4];
#pragma unroll
        for (int rr = 0; rr < 4; ++rr) acc[rr] = make_float4(0.f, 0.f, 0.f, 0.f);

        for (int k4i = 0; k4i < IN_F / 4; ++k4i) {
            float4 wv0 = *(const float4*)&sm.l.w[(4 * k4i + 0) * OUT_F + 4 * cg];
            float4 wv1 = *(const float4*)&sm.l.w[(4 * k4i + 1) * OUT_F + 4 * cg];
            float4 wv2 = *(const float4*)&sm.l.w[(4 * k4i + 2) * OUT_F + 4 * cg];
            float4 wv3 = *(const float4*)&sm.l.w[(4 * k4i + 3) * OUT_F + 4 * cg];
#pragma unroll
            for (int rr = 0; rr < 4; ++rr) {
                int r2 = (rr < rmax) ? rr : 0;
                float4 f = feat4[(size_t)(row0 + r2) * (IN_F / 4) + k4i];
                acc[rr].x += f.x * wv0.x + f.y * wv1.x + f.z * wv2.x + f.w * wv3.x;
                acc[rr].y += f.x * wv0.y + f.y * wv1.y + f.z * wv2.y + f.w * wv3.y;
                acc[rr].z += f.x * wv0.z + f.y * wv1.z + f.z * wv2.z + f.w * wv3.z;
                acc[rr].w += f.x * wv0.w + f.y * wv1.w + f.z * wv2.w + f.w * wv3.w;
            }
        }

#pragma unroll
        for (int rr = 0; rr < 4; ++rr) {
            if (rr < rmax) {
                union { __half h[4]; uint2 u; } pk;
                pk.h[0] = __float2half(acc[rr].x);
                pk.h[1] = __float2half(acc[rr].y);
                pk.h[2] = __float2half(acc[rr].z);
                pk.h[3] = __float2half(acc[rr].w);
                *(uint2*)&tmp[(size_t)(row0 + rr) * OUT_F + 4 * cg] = pk.u;
            }
        }
    }
}

// ---------------------------------------------------------------------------
// scale_tmp: one 512-thr block per src-bucket (was 256). Scan [n_bbl][C_S]
// u16 grid with count validity, LDS-histogram low bytes -> out-degree ->
// fold rsqrt into tmp.
// ---------------------------------------------------------------------------
__global__ __launch_bounds__(512) void scale_tmp(
    const unsigned short* __restrict__ bkt2,
    const unsigned short* __restrict__ cnts_s,
    const int* __restrict__ out_cnt, __half* __restrict__ tmp,
    int n_nodes, int n_bbl) {
    __shared__ int hist[R_NODES];
    __shared__ float scf[R_NODES];
    __shared__ unsigned short cnt[MAXBBL];
    int b = blockIdx.x, tid = threadIdx.x;

    if (tid < R_NODES) hist[tid] = 0;
    for (int i = tid; i < n_bbl; i += 512) cnt[i] = cnts_s[b * MAXBBL + i];
    __syncthreads();

    int sS = n_bbl * C_S;
    const uint4* g4 = (const uint4*)(bkt2 + (size_t)b * sS);
    int n4 = sS >> 3;                       // 8 u16 entries per uint4
    for (int i = tid; i < n4; i += 512) {
        int e0 = i << 3;
        int c = e0 >> 5;                    // C_S = 32
        int w = e0 & 31;
        int cc = cnt[c];
        if (w >= cc) continue;              // fully invalid oct
        uint4 v = g4[i];
        unsigned e;
        e = v.x & 0xFFFF;             atomicAdd(&hist[e], 1);
        e = v.x >> 16;    if (w + 1 < cc) atomicAdd(&hist[e], 1);
        e = v.y & 0xFFFF; if (w + 2 < cc) atomicAdd(&hist[e], 1);
        e = v.y >> 16;    if (w + 3 < cc) atomicAdd(&hist[e], 1);
        e = v.z & 0xFFFF; if (w + 4 < cc) atomicAdd(&hist[e], 1);
        e = v.z >> 16;    if (w + 5 < cc) atomicAdd(&hist[e], 1);
        e = v.w & 0xFFFF; if (w + 6 < cc) atomicAdd(&hist[e], 1);
        e = v.w >> 16;    if (w + 7 < cc) atomicAdd(&hist[e], 1);
    }
    __syncthreads();

    if (tid < R_NODES) {
        int node = b * R_NODES + tid;
        if (node < n_nodes) {
            int deg = hist[tid] + out_cnt[node];   // + rare overflow adds
            scf[tid] = rsqrtf(fmaxf((float)deg, 1.0f));
        }
    }
    __syncthreads();

#pragma unroll
    for (int p = 0; p < 2; ++p) {
        int idx = p * 512 + tid;            // 0..1023 (node, quarter)
        int rr = idx >> 2;
        int nd = b * R_NODES + rr;
        if (nd >= n_nodes) continue;
        float sc = scf[rr];
        uint4* ptr = (uint4*)(tmp + (size_t)nd * OUT_F) + (idx & 3);
        uint4 v = *ptr;
        __half2* h = (__half2*)&v;
#pragma unroll
        for (int i = 0; i < 4; ++i) {
            float2 f = __half22float2(h[i]);
            f.x *= sc; f.y *= sc;
            h[i] = __float22half2_rn(f);
        }
        *ptr = v;
    }
}

// ---------------------------------------------------------------------------
// sortgather: one 1024-thr block per 256-node dst bucket (was 512). Two grid
// scans (hist, reorder) with count validity, then 8-lane x uint2 gather with
// 128 parallel node-groups and 8-deep load batching.
// ---------------------------------------------------------------------------
__global__ __launch_bounds__(1024) void sortgather_kernel(
    const unsigned* __restrict__ bkt,
    const unsigned short* __restrict__ cnts_d,
    const int* __restrict__ in_cnt,
    const int* __restrict__ ovf, const int* __restrict__ ovf_cnt,
    const __half* __restrict__ tmp, float* __restrict__ out,
    int n_nodes, int n_bbl) {

    __shared__ unsigned srt[SRT_CAP];       // 24 KB (src ids, node-sorted)
    __shared__ unsigned short cnt[MAXBBL];
    __shared__ int hist[R_NODES];
    __shared__ int base[R_NODES];
    __shared__ int start[R_NODES];

    int b = blockIdx.x, tid = threadIdx.x;

    if (tid < R_NODES) hist[tid] = 0;
    for (int i = tid; i < n_bbl; i += 1024) cnt[i] = cnts_d[b * MAXBBL + i];
    __syncthreads();

    int sD = n_bbl * C_D;
    const uint4* g4 = (const uint4*)(bkt + (size_t)b * sD);
    int n4 = sD >> 2;                       // 4 u32 entries per uint4 (4|C_D)

    for (int i = tid; i < n4; i += 1024) {
        int e0 = i << 2;
        int c = e0 / C_D;                   // const-div -> magic mul
        int w = e0 - c * C_D;
        int cc = cnt[c];
        if (w >= cc) continue;
        uint4 v = g4[i];
        atomicAdd(&hist[v.x & RMASK], 1);
        if (w + 1 < cc) atomicAdd(&hist[v.y & RMASK], 1);
        if (w + 2 < cc) atomicAdd(&hist[v.z & RMASK], 1);
        if (w + 3 < cc) atomicAdd(&hist[v.w & RMASK], 1);
    }
    __syncthreads();

    if (tid < 64) {                      // scan 256 bins, 4/lane
        int a0 = hist[4 * tid], a1 = hist[4 * tid + 1];
        int a2 = hist[4 * tid + 2], a3 = hist[4 * tid + 3];
        int s = a0 + a1 + a2 + a3;
        int sc = s;
        for (int off = 1; off < 64; off <<= 1) {
            int v = __shfl_up(sc, off, 64);
            if (tid >= off) sc += v;
        }
        int excl = sc - s;
        base[4 * tid]     = excl;
        base[4 * tid + 1] = excl + a0;
        base[4 * tid + 2] = excl + a0 + a1;
        base[4 * tid + 3] = excl + a0 + a1 + a2;
    }
    __syncthreads();
    if (tid < R_NODES) start[tid] = base[tid];
    __syncthreads();

    for (int i = tid; i < n4; i += 1024) {
        int e0 = i << 2;
        int c = e0 / C_D;
        int w = e0 - c * C_D;
        int cc = cnt[c];
        if (w >= cc) continue;
        uint4 v = g4[i];
        int p;
        p = atomicAdd(&base[v.x & RMASK], 1);
        if (p < SRT_CAP) srt[p] = v.x >> RSHIFT;
        if (w + 1 < cc) { p = atomicAdd(&base[v.y & RMASK], 1);
                          if (p < SRT_CAP) srt[p] = v.y >> RSHIFT; }
        if (w + 2 < cc) { p = atomicAdd(&base[v.z & RMASK], 1);
                          if (p < SRT_CAP) srt[p] = v.z >> RSHIFT; }
        if (w + 3 < cc) { p = atomicAdd(&base[v.w & RMASK], 1);
                          if (p < SRT_CAP) srt[p] = v.w >> RSHIFT; }
    }
    __syncthreads();

    int g = tid >> 3;                    // group 0..127
    int c = tid & 7;                     // uint2 (4-half) column group
    int n0 = b * R_NODES;
    int novf = min(*ovf_cnt, OVF_CAP);

    for (int ln = g; ln < R_NODES; ln += 128) {
        int node = n0 + ln;
        if (node >= n_nodes) continue;
        int cntn = hist[ln];
        int st   = start[ln];

        float a0 = 0.f, a1 = 0.f, a2 = 0.f, a3 = 0.f;
        float b0 = 0.f, b1 = 0.f, b2 = 0.f, b3 = 0.f;
        int j = 0;
        for (; j + 8 <= cntn; j += 8) {
            int s0 = (int)srt[st + j + 0], s1 = (int)srt[st + j + 1];
            int s2 = (int)srt[st + j + 2], s3 = (int)srt[st + j + 3];
            int s4 = (int)srt[st + j + 4], s5 = (int)srt[st + j + 5];
            int s6 = (int)srt[st + j + 6], s7 = (int)srt[st + j + 7];
            uint2 v0 = *(const uint2*)(tmp + (size_t)s0 * OUT_F + 4 * c);
            uint2 v1 = *(const uint2*)(tmp + (size_t)s1 * OUT_F + 4 * c);
            uint2 v2 = *(const uint2*)(tmp + (size_t)s2 * OUT_F + 4 * c);
            uint2 v3 = *(const uint2*)(tmp + (size_t)s3 * OUT_F + 4 * c);
            uint2 v4 = *(const uint2*)(tmp + (size_t)s4 * OUT_F + 4 * c);
            uint2 v5 = *(const uint2*)(tmp + (size_t)s5 * OUT_F + 4 * c);
            uint2 v6 = *(const uint2*)(tmp + (size_t)s6 * OUT_F + 4 * c);
            uint2 v7 = *(const uint2*)(tmp + (size_t)s7 * OUT_F + 4 * c);
            const __half2* h;
            float2 f;
            h = (const __half2*)&v0;
            f = __half22float2(h[0]); a0 += f.x; a1 += f.y;
            f = __half22float2(h[1]); a2 += f.x; a3 += f.y;
            h = (const __half2*)&v1;
            f = __half22float2(h[0]); b0 += f.x; b1 += f.y;
            f = __half22float2(h[1]); b2 += f.x; b3 += f.y;
            h = (const __half2*)&v2;
            f = __half22float2(h[0]); a0 += f.x; a1 += f.y;
            f = __half22float2(h[1]); a2 += f.x; a3 += f.y;
            h = (const __half2*)&v3;
            f = __half22float2(h[0]); b0 += f.x; b1 += f.y;
            f = __half22float2(h[1]); b2 += f.x; b3 += f.y;
            h = (const __half2*)&v4;
            f = __half22float2(h[0]); a0 += f.x; a1 += f.y;
            f = __half22float2(h[1]); a2 += f.x; a3 += f.y;
            h = (const __half2*)&v5;
            f = __half22float2(h[0]); b0 += f.x; b1 += f.y;
            f = __half22float2(h[1]); b2 += f.x; b3 += f.y;
            h = (const __half2*)&v6;
            f = __half22float2(h[0]); a0 += f.x; a1 += f.y;
            f = __half22float2(h[1]); a2 += f.x; a3 += f.y;
            h = (const __half2*)&v7;
            f = __half22float2(h[0]); b0 += f.x; b1 += f.y;
            f = __half22float2(h[1]); b2 += f.x; b3 += f.y;
        }
        for (; j < cntn; ++j) {
            int s = (int)srt[st + j];
            uint2 v = *(const uint2*)(tmp + (size_t)s * OUT_F + 4 * c);
            const __half2* h = (const __half2*)&v;
            float2 f;
            if (j & 1) {
                f = __half22float2(h[0]); b0 += f.x; b1 += f.y;
                f = __half22float2(h[1]); b2 += f.x; b3 += f.y;
            } else {
                f = __half22float2(h[0]); a0 += f.x; a1 += f.y;
                f = __half22float2(h[1]); a2 += f.x; a3 += f.y;
            }
        }
        for (int e2 = 0; e2 < novf; ++e2) {        // ~always empty
            if (ovf[2 * e2 + 1] == node) {
                uint2 v = *(const uint2*)(tmp + (size_t)ovf[2 * e2] * OUT_F + 4 * c);
                const __half2* h = (const __half2*)&v;
                float2 f;
                f = __half22float2(h[0]); a0 += f.x; a1 += f.y;
                f = __half22float2(h[1]); a2 += f.x; a3 += f.y;
            }
        }

        float dg = (float)(cntn + in_cnt[node]);
        float sc = rsqrtf(fmaxf(dg, 1.0f));
        float4 o = make_float4((a0 + b0) * sc, (a1 + b1) * sc,
                               (a2 + b2) * sc, (a3 + b3) * sc);
        *(float4*)(out + (size_t)node * OUT_F + 4 * c) = o;
    }
}

// ---------------------------------------------------------------------------
// Fallback path (ws too small): degree + scaled-linear + atomic scatter.
// ---------------------------------------------------------------------------
__global__ void degree_kernel(const int* __restrict__ src, const int* __restrict__ dst,
                              int* __restrict__ out_cnt, int* __restrict__ in_cnt,
                              int n_edges) {
    int i = blockIdx.x * blockDim.x + threadIdx.x;
    if (i < n_edges) {
        atomicAdd(&out_cnt[src[i]], 1);
        atomicAdd(&in_cnt[dst[i]], 1);
    }
}

__global__ __launch_bounds__(256) void linear_fb(const float* __restrict__ feat,
                                                 const float* __restrict__ weight,
                                                 const int* __restrict__ out_cnt,
                                                 __half* __restrict__ tmp, int n_nodes) {
    __shared__ float w[IN_F * OUT_F];
    {
        const float4* wg = (const float4*)weight;
        float4* wsh = (float4*)w;
        for (int i = threadIdx.x; i < IN_F * OUT_F / 4; i += 256) wsh[i] = wg[i];
    }
    __syncthreads();
    int q  = threadIdx.x >> 3;
    int cg = threadIdx.x & 7;
    int row0 = blockIdx.x * 128 + q * 4;
    if (row0 >= n_nodes) return;
    int rmax = n_nodes - row0;
    if (rmax > 4) rmax = 4;
    const float4* feat4 = (const float4*)feat;
    float4 acc[4];
#pragma unroll
    for (int r = 0; r < 4; ++r) acc[r] = make_float4(0.f, 0.f, 0.f, 0.f);
    for (int k4 = 0; k4 < IN_F / 4; ++k4) {
        float4 wv0 = *(const float4*)&w[(4 * k4 + 0) * OUT_F + 4 * cg];
        float4 wv1 = *(const float4*)&w[(4 * k4 + 1) * OUT_F + 4 * cg];
        float4 wv2 = *(const float4*)&w[(4 * k4 + 2) * OUT_F + 4 * cg];
        float4 wv3 = *(const float4*)&w[(4 * k4 + 3) * OUT_F + 4 * cg];
#pragma unroll
        for (int r = 0; r < 4; ++r) {
            int rr = (r < rmax) ? r : 0;
            float4 f = feat4[(size_t)(row0 + rr) * (IN_F / 4) + k4];
            acc[r].x += f.x * wv0.x + f.y * wv1.x + f.z * wv2.x + f.w * wv3.x;
            acc[r].y += f.x * wv0.y + f.y * wv1.y + f.z * wv2.y + f.w * wv3.y;
            acc[r].z += f.x * wv0.z + f.y * wv1.z + f.z * wv2.z + f.w * wv3.z;
            acc[r].w += f.x * wv0.w + f.y * wv1.w + f.z * wv2.w + f.w * wv3.w;
        }
    }
#pragma unroll
    for (int r = 0; r < 4; ++r) {
        if (r < rmax) {
            float sc = rsqrtf(fmaxf((float)out_cnt[row0 + r], 1.0f));
            union { __half h[4]; uint2 u; } pk;
            pk.h[0] = __float2half(acc[r].x * sc);
            pk.h[1] = __float2half(acc[r].y * sc);
            pk.h[2] = __float2half(acc[r].z * sc);
            pk.h[3] = __float2half(acc[r].w * sc);
            *(uint2*)&tmp[(size_t)(row0 + r) * OUT_F + 4 * cg] = pk.u;
        }
    }
}

__global__ void scatter_kernel(const int* __restrict__ src, const int* __restrict__ dst,
                               const __half* __restrict__ tmp, float* __restrict__ out,
                               int n_edges) {
    long long t = (long long)blockIdx.x * blockDim.x + threadIdx.x;
    int e = (int)(t >> 5);
    int c = (int)(t & (OUT_F - 1));
    if (e < n_edges) {
        atomicAdd(&out[(size_t)dst[e] * OUT_F + c],
                  __half2float(tmp[(size_t)src[e] * OUT_F + c]));
    }
}

__global__ void finalize_kernel(float* __restrict__ out, const int* __restrict__ in_cnt,
                                int n_total) {
    int t = blockIdx.x * blockDim.x + threadIdx.x;
    if (t < n_total) {
        out[t] *= rsqrtf(fmaxf((float)in_cnt[t >> 5], 1.0f));
    }
}

extern "C" void kernel_launch(void* const* d_in, const int* in_sizes, int n_in,
                              void* d_out, int out_size, void* d_ws, size_t ws_size,
                              hipStream_t stream) {
    const float* feat   = (const float*)d_in[0];
    const int*   src    = (const int*)d_in[1];
    const int*   dst    = (const int*)d_in[2];
    const float* weight = (const float*)d_in[3];
    float*       out    = (float*)d_out;

    int n_nodes = in_sizes[0] / IN_F;   // 100000
    int n_edges = in_sizes[1];          // 1600000
    int n_buckets = (n_nodes + R_NODES - 1) / R_NODES;  // 391
    int n_bbl = (n_edges + EPB - 1) / EPB;              // 196
    int n_lbl = (n_nodes + 255) / 256;                  // 391

    // ws layout: [out_cnt n][in_cnt n][ovf_cnt 8][ovf 2*CAP]
    //            [cnts_d MAXNB*MAXBBL u16][cnts_s same]
    //            [bkt nb x n_bbl*C_D u32][bkt2 nb x n_bbl*C_S u16][tmp]
    int*      out_cnt = (int*)d_ws;
    int*      in_cnt  = out_cnt + n_nodes;
    int*      ovf_cnt = in_cnt + n_nodes;
    int*      ovf     = ovf_cnt + 8;
    unsigned short* cnts_d = (unsigned short*)(ovf + 2 * OVF_CAP);
    unsigned short* cnts_s = cnts_d + (size_t)MAXNB * MAXBBL;
    char*     bkt_raw = (char*)(cnts_s + (size_t)MAXNB * MAXBBL);
    unsigned* bkt     = (unsigned*)(((uintptr_t)bkt_raw + 15) & ~(uintptr_t)15);
    int sD = n_bbl * C_D;
    int sS = n_bbl * C_S;
    unsigned short* bkt2 = (unsigned short*)(bkt + (size_t)n_buckets * sD);
    char*     tmp_raw = (char*)(bkt2 + (size_t)n_buckets * sS);
    __half*   tmp     = (__half*)(((uintptr_t)tmp_raw + 15) & ~(uintptr_t)15);
    size_t    needed  = (char*)(tmp + (size_t)n_nodes * OUT_F) - (char*)d_ws;

    if (ws_size >= needed && n_buckets <= MAXNB && n_bbl <= MAXBBL) {
        hipMemsetAsync(out_cnt, 0, ((size_t)2 * n_nodes + 8) * sizeof(int), stream);
        mega_kernel<<<n_bbl + n_lbl, 512, 0, stream>>>(
            src, dst, feat, weight, out_cnt, in_cnt, bkt, bkt2,
            cnts_d, cnts_s, ovf, ovf_cnt, tmp, n_edges, n_nodes, n_bbl, n_lbl);
        scale_tmp<<<n_buckets, 512, 0, stream>>>(
            bkt2, cnts_s, out_cnt, tmp, n_nodes, n_bbl);
        sortgather_kernel<<<n_buckets, 1024, 0, stream>>>(
            bkt, cnts_d, in_cnt, ovf, ovf_cnt, tmp, out, n_nodes, n_bbl);
    } else {
        // fallback: atomic scatter
        __half* tmp_fb = (__half*)(ovf + 2 * OVF_CAP);
        hipMemsetAsync(out_cnt, 0, ((size_t)2 * n_nodes + 8) * sizeof(int), stream);
        hipMemsetAsync(d_out, 0, (size_t)out_size * sizeof(float), stream);
        degree_kernel<<<(n_edges + 255) / 256, 256, 0, stream>>>(src, dst, out_cnt, in_cnt, n_edges);
        linear_fb<<<(n_nodes + 127) / 128, 256, 0, stream>>>(feat, weight, out_cnt, tmp_fb, n_nodes);
        long long st = (long long)n_edges * OUT_F;
        scatter_kernel<<<(int)((st + 255) / 256), 256, 0, stream>>>(src, dst, tmp_fb, out, n_edges);
        finalize_kernel<<<(n_nodes * OUT_F + 255) / 256, 256, 0, stream>>>(out, in_cnt, n_nodes * OUT_F);
    }
}